// Round 1
// baseline (3314.462 us; speedup 1.0000x reference)
//
#include <hip/hip_runtime.h>
#include <cmath>

#define Bc   16
#define Cc   128
#define Nc   2000
#define Lc   128      // sequence length for mamba = C
#define DIc  4000
#define Sc   8
#define RKc  125      // DT_RANK
#define E2c  8000     // 2*DI
#define EXc  141      // DT_RANK + 2*S

// ------------------------------------------------------------------
// K1: per-(b,c) instance-norm stats over N (mean, biased var)
// grid = B*C blocks, 256 threads
// ------------------------------------------------------------------
__global__ void inorm_stats(const float* __restrict__ in,
                            float* __restrict__ mout,
                            float* __restrict__ vout) {
  int bc = blockIdx.x;
  const float* p = in + (long)bc * Nc;
  float s = 0.f, sq = 0.f;
  for (int i = threadIdx.x; i < Nc; i += blockDim.x) {
    float x = p[i]; s += x; sq += x * x;
  }
  #pragma unroll
  for (int o = 32; o > 0; o >>= 1) {
    s  += __shfl_down(s, o, 64);
    sq += __shfl_down(sq, o, 64);
  }
  __shared__ float ss[4], sqq[4];
  int w = threadIdx.x >> 6, lane = threadIdx.x & 63;
  if (lane == 0) { ss[w] = s; sqq[w] = sq; }
  __syncthreads();
  if (threadIdx.x == 0) {
    s  = ss[0] + ss[1] + ss[2] + ss[3];
    sq = sqq[0] + sqq[1] + sqq[2] + sqq[3];
    float mean = s / Nc;
    float var  = sq / Nc - mean * mean;
    mout[bc] = mean; vout[bc] = var;
  }
}

// ------------------------------------------------------------------
// K2: batch-norm scale per channel.
// inorm output has exactly zero mean per (b,c), so bn mean == 0 and
// bn var = avg_b[ v/(v+1e-3) ].  bnscale[c] = rsqrt(var + 1e-5)
// 1 block, 128 threads
// ------------------------------------------------------------------
__global__ void bn_scale(const float* __restrict__ v, float* __restrict__ bnsc) {
  int c = threadIdx.x;
  if (c >= Cc) return;
  float s = 0.f;
  for (int b = 0; b < Bc; b++) {
    float vv = v[b * Cc + c];
    s += vv / (vv + 1e-3f);
  }
  bnsc[c] = rsqrtf(s / Bc + 1e-5f);
}

// ------------------------------------------------------------------
// K3: h = relu( inorm(x) * bnscale[c] * g[c] + b[c] ), layout (b,c,n)
// ------------------------------------------------------------------
__global__ void compute_h(const float* __restrict__ in,
                          const float* __restrict__ m,
                          const float* __restrict__ v,
                          const float* __restrict__ bnsc,
                          const float* __restrict__ g,
                          const float* __restrict__ bb,
                          float* __restrict__ h, int total) {
  int i = blockIdx.x * 256 + threadIdx.x;
  if (i >= total) return;
  int bc = i / Nc;
  int c  = bc % Cc;
  float xn  = (in[i] - m[bc]) * rsqrtf(v[bc] + 1e-3f);
  float val = xn * bnsc[c] * g[c] + bb[c];
  h[i] = fmaxf(val, 0.f);
}

// ------------------------------------------------------------------
// K: prefill C[i] = bias[(i/ld)%nch] (+ addx[i] if addx != nullptr)
// ------------------------------------------------------------------
__global__ void prefill_bias(float* __restrict__ C, const float* __restrict__ bias,
                             const float* __restrict__ addx, int total, int ld, int nch) {
  int i = blockIdx.x * 256 + threadIdx.x;
  if (i >= total) return;
  float v = bias[(i / ld) % nch];
  if (addx) v += addx[i];
  C[i] = v;
}

__global__ void fill_zero(float* __restrict__ p, int total) {
  int i = blockIdx.x * 256 + threadIdx.x;
  if (i < total) p[i] = 0.f;
}

// ------------------------------------------------------------------
// K4: LayerNorm per row of 2000, with ln_w/ln_b
// grid = 2048 blocks, 256 threads
// ------------------------------------------------------------------
__global__ void ln_rows(const float* __restrict__ in,
                        const float* __restrict__ lw,
                        const float* __restrict__ lb,
                        float* __restrict__ outn) {
  int row = blockIdx.x;
  const float* p = in + (long)row * Nc;
  float s = 0.f, sq = 0.f;
  for (int i = threadIdx.x; i < Nc; i += blockDim.x) {
    float x = p[i]; s += x; sq += x * x;
  }
  #pragma unroll
  for (int o = 32; o > 0; o >>= 1) {
    s  += __shfl_down(s, o, 64);
    sq += __shfl_down(sq, o, 64);
  }
  __shared__ float ss[4], sqq[4];
  __shared__ float smean, srstd;
  int w = threadIdx.x >> 6, lane = threadIdx.x & 63;
  if (lane == 0) { ss[w] = s; sqq[w] = sq; }
  __syncthreads();
  if (threadIdx.x == 0) {
    s  = ss[0] + ss[1] + ss[2] + ss[3];
    sq = sqq[0] + sqq[1] + sqq[2] + sqq[3];
    float mean = s / Nc;
    float var  = sq / Nc - mean * mean;
    smean = mean; srstd = rsqrtf(var + 1e-5f);
  }
  __syncthreads();
  float mu = smean, rs = srstd;
  for (int i = threadIdx.x; i < Nc; i += blockDim.x) {
    outn[(long)row * Nc + i] = (p[i] - mu) * rs * lw[i] + lb[i];
  }
}

// ------------------------------------------------------------------
// Generic f32 GEMM.
//   BKMAJOR = true : C[i][j] = sum_k A[i][k] * B[j][k]   (B is (NN,K) row-major)
//   BKMAJOR = false: C[i][j] = sum_k A[i][k] * B[k][j]   (B is (K,NN) row-major)
// 128x128 tile, 256 threads, 8x8 per thread, BK=16.
// Split-K: z = batch*KS + ks; KS>1 -> atomicAdd into C (prefill C first).
// ------------------------------------------------------------------
#define GT 128
#define GBK 16
template <bool BKMAJOR>
__global__ __launch_bounds__(256)
void gemm_f32(const float* __restrict__ Ag, const float* __restrict__ Bg,
              float* Cg, int M, int NN, int K, int lda, int ldb, int ldc,
              long sA, long sB, long sC, int KS, int Klen) {
  int z = blockIdx.z;
  int batch = z / KS, ks = z - batch * KS;
  const float* A = Ag + (long)batch * sA;
  const float* B = Bg + (long)batch * sB;
  float* C = Cg + (long)batch * sC;
  int k0 = ks * Klen;
  int kend = min(K, k0 + Klen);

  int i0 = blockIdx.y * GT;
  int j0 = blockIdx.x * GT;

  __shared__ float As[GBK][GT + 4];
  __shared__ float Bs[GBK][GT + 4];

  int t = threadIdx.x;
  int jt = (t & 15) * 8;
  int it = (t >> 4) * 8;

  float acc[8][8] = {};

  for (int kt = k0; kt < kend; kt += GBK) {
    { // A tile: rows i0..+127, cols kt..+15 -> As[k][i]
      int r  = t >> 1;
      int kb = (t & 1) * 8;
      int gi = i0 + r;
      #pragma unroll
      for (int u = 0; u < 8; u++) {
        int gk = kt + kb + u;
        float vv = 0.f;
        if (gi < M && gk < kend) vv = A[(long)gi * lda + gk];
        As[kb + u][r] = vv;
      }
    }
    if (BKMAJOR) { // B tile from (NN,K): rows j0..+127, cols kt..+15 -> Bs[k][j]
      int r  = t >> 1;
      int kb = (t & 1) * 8;
      int gj = j0 + r;
      #pragma unroll
      for (int u = 0; u < 8; u++) {
        int gk = kt + kb + u;
        float vv = 0.f;
        if (gj < NN && gk < kend) vv = B[(long)gj * ldb + gk];
        Bs[kb + u][r] = vv;
      }
    } else {       // B tile from (K,NN): rows kt..+15, cols j0..+127 -> Bs[k][j]
      int kr = t >> 4;
      int jb = (t & 15) * 8;
      #pragma unroll
      for (int u = 0; u < 8; u++) {
        int gj = j0 + jb + u;
        float vv = 0.f;
        if (gj < NN && (kt + kr) < kend) vv = B[(long)(kt + kr) * ldb + gj];
        Bs[kr][jb + u] = vv;
      }
    }
    __syncthreads();
    #pragma unroll
    for (int kk = 0; kk < GBK; kk++) {
      float4 a0 = *(const float4*)&As[kk][it];
      float4 a1 = *(const float4*)&As[kk][it + 4];
      float4 b0 = *(const float4*)&Bs[kk][jt];
      float4 b1 = *(const float4*)&Bs[kk][jt + 4];
      float av[8] = {a0.x, a0.y, a0.z, a0.w, a1.x, a1.y, a1.z, a1.w};
      float bv[8] = {b0.x, b0.y, b0.z, b0.w, b1.x, b1.y, b1.z, b1.w};
      #pragma unroll
      for (int xi = 0; xi < 8; xi++)
        #pragma unroll
        for (int yi = 0; yi < 8; yi++)
          acc[xi][yi] += av[xi] * bv[yi];
    }
    __syncthreads();
  }

  #pragma unroll
  for (int xi = 0; xi < 8; xi++) {
    int gi = i0 + it + xi;
    if (gi >= M) continue;
    #pragma unroll
    for (int yi = 0; yi < 8; yi++) {
      int gj = j0 + jt + yi;
      if (gj >= NN) continue;
      long idx = (long)gi * ldc + gj;
      if (KS == 1) C[idx] = acc[xi][yi];
      else atomicAdd(&C[idx], acc[xi][yi]);
    }
  }
}

// ------------------------------------------------------------------
// K6: depthwise causal conv (DCONV=4) over l + silu.  xi = xz[...,:DI]
// out xc (b,l,d) = (2048, 4000)
// ------------------------------------------------------------------
__global__ void dwconv_silu(const float* __restrict__ xz,
                            const float4* __restrict__ cw,
                            const float* __restrict__ cb,
                            float* __restrict__ xc, int total) {
  int i = blockIdx.x * 256 + threadIdx.x;
  if (i >= total) return;
  int d  = i % DIc;
  int bl = i / DIc;
  int l  = bl % Lc;
  int b  = bl / Lc;
  float4 w = cw[d];
  float acc = cb[d];
  long rowbase = (long)(b * Lc) * E2c + d;
  int l0 = l - 3;
  if (l0     >= 0) acc += xz[rowbase + (long)l0       * E2c] * w.x;
  if (l0 + 1 >= 0) acc += xz[rowbase + (long)(l0 + 1) * E2c] * w.y;
  if (l0 + 2 >= 0) acc += xz[rowbase + (long)(l0 + 2) * E2c] * w.z;
  acc += xz[rowbase + (long)l * E2c] * w.w;
  // silu
  xc[i] = acc / (1.f + expf(-acc));
}

// ------------------------------------------------------------------
// K9: selective scan. One thread per (b,d). Reads dt-raw from dtY,
// writes final y (incl. *silu(z) and +u*D) back into dtY (safe: same
// thread, read-before-write per element).
// ------------------------------------------------------------------
__global__ void scan_kernel(float* dtY,
                            const float* __restrict__ xdbl,
                            const float* __restrict__ xc,
                            const float* __restrict__ xz,
                            const float* __restrict__ A_log,
                            const float* __restrict__ D_p,
                            const float* __restrict__ b_dt) {
  int d = blockIdx.x * blockDim.x + threadIdx.x;
  int b = blockIdx.y;
  if (d >= DIc) return;
  float Av[Sc];
  #pragma unroll
  for (int s = 0; s < Sc; s++) Av[s] = -expf(A_log[d * Sc + s]);
  float Dp  = D_p[d];
  float bdt = b_dt[d];
  float h[Sc];
  #pragma unroll
  for (int s = 0; s < Sc; s++) h[s] = 0.f;

  for (int l = 0; l < Lc; l++) {
    long row = (long)(b * Lc + l);
    float dtr = dtY[row * DIc + d] + bdt;
    float dt  = fmaxf(dtr, 0.f) + log1pf(expf(-fabsf(dtr)));  // softplus
    float u   = xc[row * DIc + d];
    float du  = dt * u;
    const float* xrow = xdbl + row * EXc;
    float y = 0.f;
    #pragma unroll
    for (int s = 0; s < Sc; s++) {
      float dA = expf(dt * Av[s]);
      h[s] = dA * h[s] + du * xrow[RKc + s];
      y += h[s] * xrow[RKc + Sc + s];
    }
    float zv = xz[row * E2c + DIc + d];
    float sz = zv / (1.f + expf(-zv));
    dtY[row * DIc + d] = (y + u * Dp) * sz;
  }
}

// ------------------------------------------------------------------
// launch
// ------------------------------------------------------------------
extern "C" void kernel_launch(void* const* d_in, const int* in_sizes, int n_in,
                              void* d_out, int out_size, void* d_ws, size_t ws_size,
                              hipStream_t stream) {
  const float* x       = (const float*)d_in[0];
  const float* bn1_g   = (const float*)d_in[1];
  const float* bn1_b   = (const float*)d_in[2];
  const float* conv1_w = (const float*)d_in[3];
  const float* conv1_b = (const float*)d_in[4];
  const float* ln_w    = (const float*)d_in[5];
  const float* ln_b    = (const float*)d_in[6];
  const float* W_in    = (const float*)d_in[7];
  const float* convm_w = (const float*)d_in[8];
  const float* convm_b = (const float*)d_in[9];
  const float* W_x     = (const float*)d_in[10];
  const float* W_dt    = (const float*)d_in[11];
  const float* b_dt    = (const float*)d_in[12];
  const float* A_log   = (const float*)d_in[13];
  const float* D_p     = (const float*)d_in[14];
  const float* W_out   = (const float*)d_in[15];
  const float* bn3_g   = (const float*)d_in[16];
  const float* bn3_b   = (const float*)d_in[17];
  const float* conv3_w = (const float*)d_in[18];
  const float* conv3_b = (const float*)d_in[19];
  float* out = (float*)d_out;
  float* ws  = (float*)d_ws;

  const int TOT  = Bc * Cc * Nc;     // 4,096,000
  const int ROWS = Bc * Lc;          // 2048

  // ws layout (floats)
  float* m1    = ws;                         // 2048
  float* v1    = ws + 2048;                  // 2048
  float* bnsc  = ws + 4096;                  // 128
  float* h     = ws + 8192;                  // 4,096,000
  float* out1  = h    + (long)TOT;           // 4,096,000
  float* outn  = out1 + (long)TOT;           // 4,096,000
  float* xz    = outn + (long)TOT;           // 16,384,000
  float* xc    = xz   + (long)ROWS * E2c;    // 8,192,000
  float* xdbl  = xc   + (long)ROWS * DIc;    // 288,768
  float* dtb   = xdbl + (long)ROWS * EXc;    // 8,192,000 (later holds y)

  dim3 b256(256);
  int gElem = (TOT + 255) / 256;

  // ---- block 1 ----
  inorm_stats<<<dim3(Bc * Cc), b256, 0, stream>>>(x, m1, v1);
  bn_scale<<<dim3(1), dim3(128), 0, stream>>>(v1, bnsc);
  compute_h<<<dim3(gElem), b256, 0, stream>>>(x, m1, v1, bnsc, bn1_g, bn1_b, h, TOT);
  prefill_bias<<<dim3(gElem), b256, 0, stream>>>(out1, conv1_b, nullptr, TOT, Nc, Cc);
  { // out1[b][o][n] += sum_c w1[o][c] * h[b][c][n]   (KS=2)
    dim3 g((Nc + GT - 1) / GT, 1, Bc * 2);
    gemm_f32<false><<<g, b256, 0, stream>>>(conv1_w, h, out1, Cc, Nc, Cc,
                                            Cc, Nc, Nc,
                                            0L, (long)Cc * Nc, (long)Cc * Nc, 2, 64);
  }

  // ---- layernorm ----
  ln_rows<<<dim3(ROWS), b256, 0, stream>>>(out1, ln_w, ln_b, outn);

  // ---- mamba: xz = outn @ W_in^T ----
  {
    dim3 g((E2c + GT - 1) / GT, (ROWS + GT - 1) / GT, 1);
    gemm_f32<true><<<g, b256, 0, stream>>>(outn, W_in, xz, ROWS, E2c, Nc,
                                           Nc, Nc, E2c, 0L, 0L, 0L, 1, Nc);
  }

  // ---- depthwise conv + silu ----
  {
    int tot = ROWS * DIc;
    dwconv_silu<<<dim3((tot + 255) / 256), b256, 0, stream>>>(
        xz, (const float4*)convm_w, convm_b, xc, tot);
  }

  // ---- xdbl = xc @ W_x^T  (NN=141, split-K=8) ----
  fill_zero<<<dim3((ROWS * EXc + 255) / 256), b256, 0, stream>>>(xdbl, ROWS * EXc);
  {
    dim3 g((EXc + GT - 1) / GT, (ROWS + GT - 1) / GT, 8);
    gemm_f32<true><<<g, b256, 0, stream>>>(xc, W_x, xdbl, ROWS, EXc, DIc,
                                           DIc, DIc, EXc, 0L, 0L, 0L, 8, 500);
  }

  // ---- dt-raw = xdbl[:, :125] @ W_dt^T ----
  {
    dim3 g((DIc + GT - 1) / GT, (ROWS + GT - 1) / GT, 1);
    gemm_f32<true><<<g, b256, 0, stream>>>(xdbl, W_dt, dtb, ROWS, DIc, RKc,
                                           EXc, RKc, DIc, 0L, 0L, 0L, 1, RKc);
  }

  // ---- selective scan (writes y in place of dtb) ----
  scan_kernel<<<dim3((DIc + 255) / 256, Bc), b256, 0, stream>>>(
      dtb, xdbl, xc, xz, A_log, D_p, b_dt);

  // ---- out1 += y @ W_out^T  (residual, split-K=2 atomic accumulate) ----
  {
    dim3 g((Nc + GT - 1) / GT, (ROWS + GT - 1) / GT, 2);
    gemm_f32<true><<<g, b256, 0, stream>>>(dtb, W_out, out1, ROWS, Nc, DIc,
                                           DIc, DIc, Nc, 0L, 0L, 0L, 2, 2000);
  }

  // ---- block 3 on out1, result accumulated onto (conv3_b + x) in d_out ----
  inorm_stats<<<dim3(Bc * Cc), b256, 0, stream>>>(out1, m1, v1);
  bn_scale<<<dim3(1), dim3(128), 0, stream>>>(v1, bnsc);
  compute_h<<<dim3(gElem), b256, 0, stream>>>(out1, m1, v1, bnsc, bn3_g, bn3_b, h, TOT);
  prefill_bias<<<dim3(gElem), b256, 0, stream>>>(out, conv3_b, x, TOT, Nc, Cc);
  {
    dim3 g((Nc + GT - 1) / GT, 1, Bc * 2);
    gemm_f32<false><<<g, b256, 0, stream>>>(conv3_w, h, out, Cc, Nc, Cc,
                                            Cc, Nc, Nc,
                                            0L, (long)Cc * Nc, (long)Cc * Nc, 2, 64);
  }
}

// Round 3
// 1468.523 us; speedup vs baseline: 2.2570x; 2.2570x over previous
//
#include <hip/hip_runtime.h>
#include <cmath>
#include <cstdint>

#define Bc   16
#define Cc   128
#define Nc   2000
#define Lc   128      // sequence length for mamba = C
#define DIc  4000
#define Sc   8
#define RKc  125      // DT_RANK
#define E2c  8000     // 2*DI
#define EXc  141      // DT_RANK + 2*S

// padded dims for MFMA gemm #1 (xz = outn @ W_in^T)
#define KP1  2016     // 2000 -> mult of 32
#define NP1  8064     // 8000 -> mult of 128

__device__ __forceinline__ unsigned short f2bf(float f) {
  union { float f; unsigned int u; } v; v.f = f;
  unsigned int r = v.u + 0x7FFFu + ((v.u >> 16) & 1u);
  return (unsigned short)(r >> 16);
}

// ------------------------------------------------------------------
// K1: per-(b,c) instance-norm stats over N (mean, biased var)
// ------------------------------------------------------------------
__global__ void inorm_stats(const float* __restrict__ in,
                            float* __restrict__ mout,
                            float* __restrict__ vout) {
  int bc = blockIdx.x;
  const float* p = in + (long)bc * Nc;
  float s = 0.f, sq = 0.f;
  for (int i = threadIdx.x; i < Nc; i += blockDim.x) {
    float x = p[i]; s += x; sq += x * x;
  }
  #pragma unroll
  for (int o = 32; o > 0; o >>= 1) {
    s  += __shfl_down(s, o, 64);
    sq += __shfl_down(sq, o, 64);
  }
  __shared__ float ss[4], sqq[4];
  int w = threadIdx.x >> 6, lane = threadIdx.x & 63;
  if (lane == 0) { ss[w] = s; sqq[w] = sq; }
  __syncthreads();
  if (threadIdx.x == 0) {
    s  = ss[0] + ss[1] + ss[2] + ss[3];
    sq = sqq[0] + sqq[1] + sqq[2] + sqq[3];
    float mean = s / Nc;
    float var  = sq / Nc - mean * mean;
    mout[bc] = mean; vout[bc] = var;
  }
}

// ------------------------------------------------------------------
// K2: bn scale; inorm output has zero mean per (b,c) so bn mean==0,
// bn var = avg_b[ v/(v+1e-3) ]
// ------------------------------------------------------------------
__global__ void bn_scale(const float* __restrict__ v, float* __restrict__ bnsc) {
  int c = threadIdx.x;
  if (c >= Cc) return;
  float s = 0.f;
  for (int b = 0; b < Bc; b++) {
    float vv = v[b * Cc + c];
    s += vv / (vv + 1e-3f);
  }
  bnsc[c] = rsqrtf(s / Bc + 1e-5f);
}

// ------------------------------------------------------------------
// K3: h = relu( inorm(x) * bnscale[c] * g[c] + b[c] )
// ------------------------------------------------------------------
__global__ void compute_h(const float* __restrict__ in,
                          const float* __restrict__ m,
                          const float* __restrict__ v,
                          const float* __restrict__ bnsc,
                          const float* __restrict__ g,
                          const float* __restrict__ bb,
                          float* __restrict__ h, int total) {
  int i = blockIdx.x * 256 + threadIdx.x;
  if (i >= total) return;
  int bc = i / Nc;
  int c  = bc % Cc;
  float xn  = (in[i] - m[bc]) * rsqrtf(v[bc] + 1e-3f);
  float val = xn * bnsc[c] * g[c] + bb[c];
  h[i] = fmaxf(val, 0.f);
}

__global__ void prefill_bias(float* __restrict__ C, const float* __restrict__ bias,
                             const float* __restrict__ addx, int total, int ld, int nch) {
  int i = blockIdx.x * 256 + threadIdx.x;
  if (i >= total) return;
  float v = bias[(i / ld) % nch];
  if (addx) v += addx[i];
  C[i] = v;
}

__global__ void fill_zero(float* __restrict__ p, int total) {
  int i = blockIdx.x * 256 + threadIdx.x;
  if (i < total) p[i] = 0.f;
}

// ------------------------------------------------------------------
// convert f32 (Rsrc x Csrc) to bf16 (R x Cdst) with zero padding
// ------------------------------------------------------------------
__global__ void cvt_pad_bf16(const float* __restrict__ src, unsigned short* __restrict__ dst,
                             int R, int Cdst, int Rsrc, int Csrc) {
  long i = (long)blockIdx.x * 256 + threadIdx.x;
  long total = (long)R * Cdst;
  if (i >= total) return;
  int r = (int)(i / Cdst), c = (int)(i - (long)r * Cdst);
  float v = (r < Rsrc && c < Csrc) ? src[(long)r * Csrc + c] : 0.f;
  dst[i] = f2bf(v);
}

// ------------------------------------------------------------------
// K4: LayerNorm rows -> writes bf16, K-padded to KP1 with zeros
// ------------------------------------------------------------------
__global__ void ln_rows(const float* __restrict__ in,
                        const float* __restrict__ lw,
                        const float* __restrict__ lb,
                        unsigned short* __restrict__ An) {
  int row = blockIdx.x;
  const float* p = in + (long)row * Nc;
  float s = 0.f, sq = 0.f;
  for (int i = threadIdx.x; i < Nc; i += blockDim.x) {
    float x = p[i]; s += x; sq += x * x;
  }
  #pragma unroll
  for (int o = 32; o > 0; o >>= 1) {
    s  += __shfl_down(s, o, 64);
    sq += __shfl_down(sq, o, 64);
  }
  __shared__ float ss[4], sqq[4];
  __shared__ float smean, srstd;
  int w = threadIdx.x >> 6, lane = threadIdx.x & 63;
  if (lane == 0) { ss[w] = s; sqq[w] = sq; }
  __syncthreads();
  if (threadIdx.x == 0) {
    s  = ss[0] + ss[1] + ss[2] + ss[3];
    sq = sqq[0] + sqq[1] + sqq[2] + sqq[3];
    float mean = s / Nc;
    float var  = sq / Nc - mean * mean;
    smean = mean; srstd = rsqrtf(var + 1e-5f);
  }
  __syncthreads();
  float mu = smean, rs = srstd;
  for (int i = threadIdx.x; i < KP1; i += blockDim.x) {
    float v = 0.f;
    if (i < Nc) v = (p[i] - mu) * rs * lw[i] + lb[i];
    An[(long)row * KP1 + i] = f2bf(v);
  }
}

// ------------------------------------------------------------------
// Generic f32 GEMM (kept for the small/skinny shapes).
// ------------------------------------------------------------------
#define GT 128
#define GBK 16
template <bool BKMAJOR>
__global__ __launch_bounds__(256)
void gemm_f32(const float* __restrict__ Ag, const float* __restrict__ Bg,
              float* Cg, int M, int NN, int K, int lda, int ldb, int ldc,
              long sA, long sB, long sC, int KS, int Klen) {
  int z = blockIdx.z;
  int batch = z / KS, ks = z - batch * KS;
  const float* A = Ag + (long)batch * sA;
  const float* B = Bg + (long)batch * sB;
  float* C = Cg + (long)batch * sC;
  int k0 = ks * Klen;
  int kend = min(K, k0 + Klen);

  int i0 = blockIdx.y * GT;
  int j0 = blockIdx.x * GT;

  __shared__ float As[GBK][GT + 4];
  __shared__ float Bs[GBK][GT + 4];

  int t = threadIdx.x;
  int jt = (t & 15) * 8;
  int it = (t >> 4) * 8;

  float acc[8][8] = {};

  for (int kt = k0; kt < kend; kt += GBK) {
    {
      int r  = t >> 1;
      int kb = (t & 1) * 8;
      int gi = i0 + r;
      #pragma unroll
      for (int u = 0; u < 8; u++) {
        int gk = kt + kb + u;
        float vv = 0.f;
        if (gi < M && gk < kend) vv = A[(long)gi * lda + gk];
        As[kb + u][r] = vv;
      }
    }
    if (BKMAJOR) {
      int r  = t >> 1;
      int kb = (t & 1) * 8;
      int gj = j0 + r;
      #pragma unroll
      for (int u = 0; u < 8; u++) {
        int gk = kt + kb + u;
        float vv = 0.f;
        if (gj < NN && gk < kend) vv = B[(long)gj * ldb + gk];
        Bs[kb + u][r] = vv;
      }
    } else {
      int kr = t >> 4;
      int jb = (t & 15) * 8;
      #pragma unroll
      for (int u = 0; u < 8; u++) {
        int gj = j0 + jb + u;
        float vv = 0.f;
        if (gj < NN && (kt + kr) < kend) vv = B[(long)(kt + kr) * ldb + gj];
        Bs[kr][jb + u] = vv;
      }
    }
    __syncthreads();
    #pragma unroll
    for (int kk = 0; kk < GBK; kk++) {
      float4 a0 = *(const float4*)&As[kk][it];
      float4 a1 = *(const float4*)&As[kk][it + 4];
      float4 b0 = *(const float4*)&Bs[kk][jt];
      float4 b1 = *(const float4*)&Bs[kk][jt + 4];
      float av[8] = {a0.x, a0.y, a0.z, a0.w, a1.x, a1.y, a1.z, a1.w};
      float bv[8] = {b0.x, b0.y, b0.z, b0.w, b1.x, b1.y, b1.z, b1.w};
      #pragma unroll
      for (int xi = 0; xi < 8; xi++)
        #pragma unroll
        for (int yi = 0; yi < 8; yi++)
          acc[xi][yi] += av[xi] * bv[yi];
    }
    __syncthreads();
  }

  #pragma unroll
  for (int xi = 0; xi < 8; xi++) {
    int gi = i0 + it + xi;
    if (gi >= M) continue;
    #pragma unroll
    for (int yi = 0; yi < 8; yi++) {
      int gj = j0 + jt + yi;
      if (gj >= NN) continue;
      long idx = (long)gi * ldc + gj;
      if (KS == 1) C[idx] = acc[xi][yi];
      else atomicAdd(&C[idx], acc[xi][yi]);
    }
  }
}

// ------------------------------------------------------------------
// bf16 MFMA GEMM, B^T layout: C[i][j] = sum_k A[i][k] * B[j][k]
// 128x128 tile, 4 waves (2x2), each wave 4x4 of mfma_f32_16x16x32_bf16.
// global_load_lds width=16 staging. K (and Klen splits) multiple of 32.
// M multiple of 128; B rows padded to gridDim.x*128; j guarded by NN.
// KS>1 -> atomicAdd (C prefilled). KS==1 -> plain store.
// ------------------------------------------------------------------
typedef short v8s __attribute__((ext_vector_type(8)));
typedef float v4f __attribute__((ext_vector_type(4)));

typedef const __attribute__((address_space(1))) unsigned int* as1_cu32p;
typedef __attribute__((address_space(3))) unsigned int* as3_u32p;

__device__ __forceinline__ void gload_lds16(const unsigned short* g, unsigned short* l) {
  __builtin_amdgcn_global_load_lds((as1_cu32p)(uintptr_t)g,
                                   (as3_u32p)(uintptr_t)l, 16, 0, 0);
}

__global__ __launch_bounds__(256)
void gemm_mfma_bt(const unsigned short* __restrict__ A,
                  const unsigned short* __restrict__ B,
                  float* C, int NN, int K, int lda, int ldb, int ldc,
                  int KS, int Klen) {
  __shared__ unsigned short As[128 * 32];
  __shared__ unsigned short Bs[128 * 32];

  int ks = blockIdx.z;
  int k0 = ks * Klen;
  int kend = min(K, k0 + Klen);

  int i0 = blockIdx.y * 128;
  int j0 = blockIdx.x * 128;

  int t = threadIdx.x;
  int wave = t >> 6, lane = t & 63;
  int wm = wave >> 1, wn = wave & 1;

  // staging: wave handles 32 rows of As and 32 rows of Bs (2 issues each)
  int srow = lane >> 2;     // 0..15
  int scol = lane & 3;      // k-chunk (8 bf16 = 16B)
  const unsigned short* gA0 = A + (long)(i0 + wave * 32 + srow) * lda + scol * 8;
  const unsigned short* gA1 = gA0 + (long)16 * lda;
  const unsigned short* gB0 = B + (long)(j0 + wave * 32 + srow) * ldb + scol * 8;
  const unsigned short* gB1 = gB0 + (long)16 * ldb;
  unsigned short* lA0 = As + (wave * 32) * 32;
  unsigned short* lA1 = As + (wave * 32 + 16) * 32;
  unsigned short* lB0 = Bs + (wave * 32) * 32;
  unsigned short* lB1 = Bs + (wave * 32 + 16) * 32;

  int fr = lane & 15;       // input-frag row index
  int kq = lane >> 4;       // k-quad (8 elements each)

  v4f acc[4][4] = {};

  for (int kt = k0; kt < kend; kt += 32) {
    gload_lds16(gA0 + kt, lA0);
    gload_lds16(gA1 + kt, lA1);
    gload_lds16(gB0 + kt, lB0);
    gload_lds16(gB1 + kt, lB1);
    __syncthreads();

    v8s af[4], bfr[4];
    #pragma unroll
    for (int mt = 0; mt < 4; mt++)
      af[mt] = *(const v8s*)&As[(wm * 64 + mt * 16 + fr) * 32 + kq * 8];
    #pragma unroll
    for (int nt = 0; nt < 4; nt++)
      bfr[nt] = *(const v8s*)&Bs[(wn * 64 + nt * 16 + fr) * 32 + kq * 8];

    #pragma unroll
    for (int mt = 0; mt < 4; mt++)
      #pragma unroll
      for (int nt = 0; nt < 4; nt++)
        acc[mt][nt] = __builtin_amdgcn_mfma_f32_16x16x32_bf16(
            af[mt], bfr[nt], acc[mt][nt], 0, 0, 0);
    __syncthreads();
  }

  // C/D layout: row=(lane>>4)*4+reg (A's m), col=lane&15 (B's n)
  int orow = (lane >> 4) * 4;
  int ocol = lane & 15;
  #pragma unroll
  for (int mt = 0; mt < 4; mt++) {
    #pragma unroll
    for (int nt = 0; nt < 4; nt++) {
      int gi = i0 + wm * 64 + mt * 16 + orow;
      int gj = j0 + wn * 64 + nt * 16 + ocol;
      if (gj >= NN) continue;
      #pragma unroll
      for (int r = 0; r < 4; r++) {
        long idx = (long)(gi + r) * ldc + gj;
        if (KS == 1) C[idx] = acc[mt][nt][r];
        else atomicAdd(&C[idx], acc[mt][nt][r]);
      }
    }
  }
}

// ------------------------------------------------------------------
// K6: depthwise causal conv (DCONV=4) + silu
// ------------------------------------------------------------------
__global__ void dwconv_silu(const float* __restrict__ xz,
                            const float4* __restrict__ cw,
                            const float* __restrict__ cb,
                            float* __restrict__ xc, int total) {
  int i = blockIdx.x * 256 + threadIdx.x;
  if (i >= total) return;
  int d  = i % DIc;
  int bl = i / DIc;
  int l  = bl % Lc;
  int b  = bl / Lc;
  float4 w = cw[d];
  float acc = cb[d];
  long rowbase = (long)(b * Lc) * E2c + d;
  int l0 = l - 3;
  if (l0     >= 0) acc += xz[rowbase + (long)l0       * E2c] * w.x;
  if (l0 + 1 >= 0) acc += xz[rowbase + (long)(l0 + 1) * E2c] * w.y;
  if (l0 + 2 >= 0) acc += xz[rowbase + (long)(l0 + 2) * E2c] * w.z;
  acc += xz[rowbase + (long)l * E2c] * w.w;
  xc[i] = acc / (1.f + expf(-acc));
}

// ------------------------------------------------------------------
// K9: selective scan. Reads dt-raw (f32), writes y (bf16) incl.
// *silu(z) and +u*D into yb (2048 x 4000 bf16).
// ------------------------------------------------------------------
__global__ void scan_kernel(const float* __restrict__ dtb,
                            const float* __restrict__ xdbl,
                            const float* __restrict__ xc,
                            const float* __restrict__ xz,
                            const float* __restrict__ A_log,
                            const float* __restrict__ D_p,
                            const float* __restrict__ b_dt,
                            unsigned short* __restrict__ yb) {
  int d = blockIdx.x * blockDim.x + threadIdx.x;
  int b = blockIdx.y;
  if (d >= DIc) return;
  float Av[Sc];
  #pragma unroll
  for (int s = 0; s < Sc; s++) Av[s] = -expf(A_log[d * Sc + s]);
  float Dp  = D_p[d];
  float bdt = b_dt[d];
  float h[Sc];
  #pragma unroll
  for (int s = 0; s < Sc; s++) h[s] = 0.f;

  for (int l = 0; l < Lc; l++) {
    long row = (long)(b * Lc + l);
    float dtr = dtb[row * DIc + d] + bdt;
    float dt  = fmaxf(dtr, 0.f) + log1pf(expf(-fabsf(dtr)));
    float u   = xc[row * DIc + d];
    float du  = dt * u;
    const float* xrow = xdbl + row * EXc;
    float y = 0.f;
    #pragma unroll
    for (int s = 0; s < Sc; s++) {
      float dA = expf(dt * Av[s]);
      h[s] = dA * h[s] + du * xrow[RKc + s];
      y += h[s] * xrow[RKc + Sc + s];
    }
    float zv = xz[row * E2c + DIc + d];
    float sz = zv / (1.f + expf(-zv));
    yb[row * DIc + d] = f2bf((y + u * Dp) * sz);
  }
}

// ------------------------------------------------------------------
// launch
// ------------------------------------------------------------------
extern "C" void kernel_launch(void* const* d_in, const int* in_sizes, int n_in,
                              void* d_out, int out_size, void* d_ws, size_t ws_size,
                              hipStream_t stream) {
  const float* x       = (const float*)d_in[0];
  const float* bn1_g   = (const float*)d_in[1];
  const float* bn1_b   = (const float*)d_in[2];
  const float* conv1_w = (const float*)d_in[3];
  const float* conv1_b = (const float*)d_in[4];
  const float* ln_w    = (const float*)d_in[5];
  const float* ln_b    = (const float*)d_in[6];
  const float* W_in    = (const float*)d_in[7];
  const float* convm_w = (const float*)d_in[8];
  const float* convm_b = (const float*)d_in[9];
  const float* W_x     = (const float*)d_in[10];
  const float* W_dt    = (const float*)d_in[11];
  const float* b_dt    = (const float*)d_in[12];
  const float* A_log   = (const float*)d_in[13];
  const float* D_p     = (const float*)d_in[14];
  const float* W_out   = (const float*)d_in[15];
  const float* bn3_g   = (const float*)d_in[16];
  const float* bn3_b   = (const float*)d_in[17];
  const float* conv3_w = (const float*)d_in[18];
  const float* conv3_b = (const float*)d_in[19];
  float* out = (float*)d_out;
  float* ws  = (float*)d_ws;

  const int TOT  = Bc * Cc * Nc;     // 4,096,000
  const int ROWS = Bc * Lc;          // 2048

  // ws layout (floats) — bf16 buffers live in dead regions:
  float* m1    = ws;                         // 2048
  float* v1    = ws + 2048;                  // 2048
  float* bnsc  = ws + 4096;                  // 128
  float* h     = ws + 8192;                  // 4,096,000 f32
  float* out1  = h    + (long)TOT;           // 4,096,000 f32
  float* outn  = out1 + (long)TOT;           // 4,096,000 f32 region
  float* xz    = outn + (long)TOT;           // 16,384,000 f32
  float* xc    = xz   + (long)ROWS * E2c;    // 8,192,000 f32
  float* xdbl  = xc   + (long)ROWS * DIc;    // 288,768 f32
  float* dtb   = xdbl + (long)ROWS * EXc;    // 8,192,000 f32

  // bf16 aliases (lifetimes verified against stream order):
  unsigned short* An    = (unsigned short*)outn;  // 2048x2016 bf16 (8.3MB < 16MB)
  unsigned short* Bwin  = (unsigned short*)dtb;   // 8064x2016 bf16 (32.5MB < 32.8MB); dead before dt-gemm writes dtb
  unsigned short* Bwout = (unsigned short*)h;     // 2048x4000 bf16 (=16.384MB); h dead between conv1-gemm and block-3 compute_h
  unsigned short* yb    = (unsigned short*)out;   // 2048x4000 bf16 (=16.384MB); d_out dead until block-3 prefill

  dim3 b256(256);
  int gElem = (TOT + 255) / 256;

  // ---- block 1 ----
  inorm_stats<<<dim3(Bc * Cc), b256, 0, stream>>>(x, m1, v1);
  bn_scale<<<dim3(1), dim3(128), 0, stream>>>(v1, bnsc);
  compute_h<<<dim3(gElem), b256, 0, stream>>>(x, m1, v1, bnsc, bn1_g, bn1_b, h, TOT);
  prefill_bias<<<dim3(gElem), b256, 0, stream>>>(out1, conv1_b, nullptr, TOT, Nc, Cc);
  { // out1[b][o][n] += sum_c w1[o][c] * h[b][c][n]   (KS=2)
    dim3 g((Nc + GT - 1) / GT, 1, Bc * 2);
    gemm_f32<false><<<g, b256, 0, stream>>>(conv1_w, h, out1, Cc, Nc, Cc,
                                            Cc, Nc, Nc,
                                            0L, (long)Cc * Nc, (long)Cc * Nc, 2, 64);
  }

  // ---- layernorm -> bf16 An (K-padded) ----
  ln_rows<<<dim3(ROWS), b256, 0, stream>>>(out1, ln_w, ln_b, An);

  // ---- W_in -> bf16 padded (8064 x 2016), into dead dtb region ----
  {
    long tot = (long)NP1 * KP1;
    cvt_pad_bf16<<<dim3((unsigned)((tot + 255) / 256)), b256, 0, stream>>>(
        W_in, Bwin, NP1, KP1, E2c, Nc);
  }

  // ---- xz = outn @ W_in^T  (MFMA bf16) ----
  {
    dim3 g(NP1 / 128, ROWS / 128, 1);
    gemm_mfma_bt<<<g, b256, 0, stream>>>(An, Bwin, xz, E2c, KP1, KP1, KP1, E2c,
                                         1, KP1);
  }

  // ---- depthwise conv + silu ----
  {
    int tot = ROWS * DIc;
    dwconv_silu<<<dim3((tot + 255) / 256), b256, 0, stream>>>(
        xz, (const float4*)convm_w, convm_b, xc, tot);
  }

  // ---- xdbl = xc @ W_x^T  (NN=141, split-K=8, f32) ----
  fill_zero<<<dim3((ROWS * EXc + 255) / 256), b256, 0, stream>>>(xdbl, ROWS * EXc);
  {
    dim3 g((EXc + GT - 1) / GT, (ROWS + GT - 1) / GT, 8);
    gemm_f32<true><<<g, b256, 0, stream>>>(xc, W_x, xdbl, ROWS, EXc, DIc,
                                           DIc, DIc, EXc, 0L, 0L, 0L, 8, 500);
  }

  // ---- dt-raw = xdbl[:, :125] @ W_dt^T  (f32) — overwrites Bwin region ----
  {
    dim3 g((DIc + GT - 1) / GT, (ROWS + GT - 1) / GT, 1);
    gemm_f32<true><<<g, b256, 0, stream>>>(xdbl, W_dt, dtb, ROWS, DIc, RKc,
                                           EXc, RKc, DIc, 0L, 0L, 0L, 1, RKc);
  }

  // ---- W_out -> bf16 padded (2048 x 4000), into dead h region ----
  {
    long tot = (long)2048 * DIc;
    cvt_pad_bf16<<<dim3((unsigned)((tot + 255) / 256)), b256, 0, stream>>>(
        W_out, Bwout, 2048, DIc, Nc, DIc);
  }

  // ---- selective scan -> yb bf16 (in d_out region) ----
  scan_kernel<<<dim3((DIc + 255) / 256, Bc), b256, 0, stream>>>(
      dtb, xdbl, xc, xz, A_log, D_p, b_dt, yb);

  // ---- out1 += y @ W_out^T  (MFMA bf16, split-K=2 atomic accumulate) ----
  {
    dim3 g(2048 / 128, ROWS / 128, 2);
    gemm_mfma_bt<<<g, b256, 0, stream>>>(yb, Bwout, out1, Nc, DIc, DIc, DIc, Nc,
                                         2, 2048);
  }

  // ---- block 3 on out1, accumulated onto (conv3_b + x) in d_out ----
  inorm_stats<<<dim3(Bc * Cc), b256, 0, stream>>>(out1, m1, v1);
  bn_scale<<<dim3(1), dim3(128), 0, stream>>>(v1, bnsc);
  compute_h<<<dim3(gElem), b256, 0, stream>>>(out1, m1, v1, bnsc, bn3_g, bn3_b, h, TOT);
  prefill_bias<<<dim3(gElem), b256, 0, stream>>>(out, conv3_b, x, TOT, Nc, Cc);
  {
    dim3 g((Nc + GT - 1) / GT, 1, Bc * 2);
    gemm_f32<false><<<g, b256, 0, stream>>>(conv3_w, h, out, Cc, Nc, Cc,
                                            Cc, Nc, Nc,
                                            0L, (long)Cc * Nc, (long)Cc * Nc, 2, 64);
  }
}

// Round 4
// 953.327 us; speedup vs baseline: 3.4767x; 1.5404x over previous
//
#include <hip/hip_runtime.h>
#include <cmath>
#include <cstdint>

#define Bc   16
#define Cc   128
#define Nc   2000
#define Lc   128      // sequence length for mamba = C
#define DIc  4000
#define Sc   8
#define RKc  125      // DT_RANK
#define E2c  8000     // 2*DI
#define EXc  141      // DT_RANK + 2*S

// padded dims for MFMA gemm #1 (xz = outn @ W_in^T)
#define KP1  2016     // 2000 -> mult of 32
#define NP1  8064     // 8000 -> mult of 128

__device__ __forceinline__ unsigned short f2bf(float f) {
  union { float f; unsigned int u; } v; v.f = f;
  unsigned int r = v.u + 0x7FFFu + ((v.u >> 16) & 1u);
  return (unsigned short)(r >> 16);
}

// ------------------------------------------------------------------
// K1: per-(b,c) instance-norm stats over N (mean, biased var)
// ------------------------------------------------------------------
__global__ void inorm_stats(const float* __restrict__ in,
                            float* __restrict__ mout,
                            float* __restrict__ vout) {
  int bc = blockIdx.x;
  const float* p = in + (long)bc * Nc;
  float s = 0.f, sq = 0.f;
  for (int i = threadIdx.x; i < Nc; i += blockDim.x) {
    float x = p[i]; s += x; sq += x * x;
  }
  #pragma unroll
  for (int o = 32; o > 0; o >>= 1) {
    s  += __shfl_down(s, o, 64);
    sq += __shfl_down(sq, o, 64);
  }
  __shared__ float ss[4], sqq[4];
  int w = threadIdx.x >> 6, lane = threadIdx.x & 63;
  if (lane == 0) { ss[w] = s; sqq[w] = sq; }
  __syncthreads();
  if (threadIdx.x == 0) {
    s  = ss[0] + ss[1] + ss[2] + ss[3];
    sq = sqq[0] + sqq[1] + sqq[2] + sqq[3];
    float mean = s / Nc;
    float var  = sq / Nc - mean * mean;
    mout[bc] = mean; vout[bc] = var;
  }
}

// ------------------------------------------------------------------
// K2: bn scale; inorm output has zero mean per (b,c) so bn mean==0,
// bn var = avg_b[ v/(v+1e-3) ]
// ------------------------------------------------------------------
__global__ void bn_scale(const float* __restrict__ v, float* __restrict__ bnsc) {
  int c = threadIdx.x;
  if (c >= Cc) return;
  float s = 0.f;
  for (int b = 0; b < Bc; b++) {
    float vv = v[b * Cc + c];
    s += vv / (vv + 1e-3f);
  }
  bnsc[c] = rsqrtf(s / Bc + 1e-5f);
}

// ------------------------------------------------------------------
// K3: h = relu( inorm(x) * bnscale[c] * g[c] + b[c] )
// ------------------------------------------------------------------
__global__ void compute_h(const float* __restrict__ in,
                          const float* __restrict__ m,
                          const float* __restrict__ v,
                          const float* __restrict__ bnsc,
                          const float* __restrict__ g,
                          const float* __restrict__ bb,
                          float* __restrict__ h, int total) {
  int i = blockIdx.x * 256 + threadIdx.x;
  if (i >= total) return;
  int bc = i / Nc;
  int c  = bc % Cc;
  float xn  = (in[i] - m[bc]) * rsqrtf(v[bc] + 1e-3f);
  float val = xn * bnsc[c] * g[c] + bb[c];
  h[i] = fmaxf(val, 0.f);
}

// ------------------------------------------------------------------
// reduce ns slices (each `stride` apart) into dst; accum!=0 -> dst += sum
// ------------------------------------------------------------------
__global__ void reduce_slices(const float* __restrict__ sl, float* __restrict__ dst,
                              long stride, int ns, int total, int accum) {
  int i = blockIdx.x * 256 + threadIdx.x;
  if (i >= total) return;
  float s = accum ? dst[i] : 0.f;
  for (int k = 0; k < ns; k++) s += sl[(long)k * stride + i];
  dst[i] = s;
}

// ------------------------------------------------------------------
// convert f32 (Rsrc x Csrc) to bf16 (R x Cdst) with zero padding
// ------------------------------------------------------------------
__global__ void cvt_pad_bf16(const float* __restrict__ src, unsigned short* __restrict__ dst,
                             int R, int Cdst, int Rsrc, int Csrc) {
  long i = (long)blockIdx.x * 256 + threadIdx.x;
  long total = (long)R * Cdst;
  if (i >= total) return;
  int r = (int)(i / Cdst), c = (int)(i - (long)r * Cdst);
  float v = (r < Rsrc && c < Csrc) ? src[(long)r * Csrc + c] : 0.f;
  dst[i] = f2bf(v);
}

// ------------------------------------------------------------------
// K4: LayerNorm rows -> writes bf16, K-padded to KP1 with zeros
// ------------------------------------------------------------------
__global__ void ln_rows(const float* __restrict__ in,
                        const float* __restrict__ lw,
                        const float* __restrict__ lb,
                        unsigned short* __restrict__ An) {
  int row = blockIdx.x;
  const float* p = in + (long)row * Nc;
  float s = 0.f, sq = 0.f;
  for (int i = threadIdx.x; i < Nc; i += blockDim.x) {
    float x = p[i]; s += x; sq += x * x;
  }
  #pragma unroll
  for (int o = 32; o > 0; o >>= 1) {
    s  += __shfl_down(s, o, 64);
    sq += __shfl_down(sq, o, 64);
  }
  __shared__ float ss[4], sqq[4];
  __shared__ float smean, srstd;
  int w = threadIdx.x >> 6, lane = threadIdx.x & 63;
  if (lane == 0) { ss[w] = s; sqq[w] = sq; }
  __syncthreads();
  if (threadIdx.x == 0) {
    s  = ss[0] + ss[1] + ss[2] + ss[3];
    sq = sqq[0] + sqq[1] + sqq[2] + sqq[3];
    float mean = s / Nc;
    float var  = sq / Nc - mean * mean;
    smean = mean; srstd = rsqrtf(var + 1e-5f);
  }
  __syncthreads();
  float mu = smean, rs = srstd;
  for (int i = threadIdx.x; i < KP1; i += blockDim.x) {
    float v = 0.f;
    if (i < Nc) v = (p[i] - mu) * rs * lw[i] + lb[i];
    An[(long)row * KP1 + i] = f2bf(v);
  }
}

// ------------------------------------------------------------------
// Generic f32 GEMM — NO atomics. Split-K writes plain-store slices
// (ks * sliceStride apart); caller reduces. Epilogue folds per-row
// bias[gi] and elementwise addp (batched with stride sC).
// ------------------------------------------------------------------
#define GT 128
#define GBK 16
template <bool BKMAJOR>
__global__ __launch_bounds__(256)
void gemm_f32(const float* __restrict__ Ag, const float* __restrict__ Bg,
              float* Cg, int M, int NN, int K, int lda, int ldb, int ldc,
              long sA, long sB, long sC, int KS, int Klen,
              long sliceStride, const float* __restrict__ bias,
              const float* __restrict__ addp) {
  int z = blockIdx.z;
  int batch = z / KS, ks = z - batch * KS;
  const float* A = Ag + (long)batch * sA;
  const float* B = Bg + (long)batch * sB;
  float* C = Cg + (long)batch * sC + (long)ks * sliceStride;
  const float* X = addp ? addp + (long)batch * sC : nullptr;
  int k0 = ks * Klen;
  int kend = min(K, k0 + Klen);

  int i0 = blockIdx.y * GT;
  int j0 = blockIdx.x * GT;

  __shared__ float As[GBK][GT + 4];
  __shared__ float Bs[GBK][GT + 4];

  int t = threadIdx.x;
  int jt = (t & 15) * 8;
  int it = (t >> 4) * 8;

  float acc[8][8] = {};

  for (int kt = k0; kt < kend; kt += GBK) {
    {
      int r  = t >> 1;
      int kb = (t & 1) * 8;
      int gi = i0 + r;
      #pragma unroll
      for (int u = 0; u < 8; u++) {
        int gk = kt + kb + u;
        float vv = 0.f;
        if (gi < M && gk < kend) vv = A[(long)gi * lda + gk];
        As[kb + u][r] = vv;
      }
    }
    if (BKMAJOR) {
      int r  = t >> 1;
      int kb = (t & 1) * 8;
      int gj = j0 + r;
      #pragma unroll
      for (int u = 0; u < 8; u++) {
        int gk = kt + kb + u;
        float vv = 0.f;
        if (gj < NN && gk < kend) vv = B[(long)gj * ldb + gk];
        Bs[kb + u][r] = vv;
      }
    } else {
      int kr = t >> 4;
      int jb = (t & 15) * 8;
      #pragma unroll
      for (int u = 0; u < 8; u++) {
        int gj = j0 + jb + u;
        float vv = 0.f;
        if (gj < NN && (kt + kr) < kend) vv = B[(long)(kt + kr) * ldb + gj];
        Bs[kr][jb + u] = vv;
      }
    }
    __syncthreads();
    #pragma unroll
    for (int kk = 0; kk < GBK; kk++) {
      float4 a0 = *(const float4*)&As[kk][it];
      float4 a1 = *(const float4*)&As[kk][it + 4];
      float4 b0 = *(const float4*)&Bs[kk][jt];
      float4 b1 = *(const float4*)&Bs[kk][jt + 4];
      float av[8] = {a0.x, a0.y, a0.z, a0.w, a1.x, a1.y, a1.z, a1.w};
      float bv[8] = {b0.x, b0.y, b0.z, b0.w, b1.x, b1.y, b1.z, b1.w};
      #pragma unroll
      for (int xi = 0; xi < 8; xi++)
        #pragma unroll
        for (int yi = 0; yi < 8; yi++)
          acc[xi][yi] += av[xi] * bv[yi];
    }
    __syncthreads();
  }

  #pragma unroll
  for (int xi = 0; xi < 8; xi++) {
    int gi = i0 + it + xi;
    if (gi >= M) continue;
    float bv = bias ? bias[gi] : 0.f;
    #pragma unroll
    for (int yi = 0; yi < 8; yi++) {
      int gj = j0 + jt + yi;
      if (gj >= NN) continue;
      long idx = (long)gi * ldc + gj;
      float v = acc[xi][yi] + bv;
      if (X) v += X[idx];
      C[idx] = v;
    }
  }
}

// ------------------------------------------------------------------
// bf16 MFMA GEMM, B^T layout: C[i][j] = sum_k A[i][k] * B[j][k]
// 128x128 tile, 4 waves (2x2), each wave 4x4 of mfma_f32_16x16x32_bf16.
// global_load_lds width=16 staging. K (and Klen splits) multiple of 32.
// Split-K writes plain-store slices ks*sliceStride apart (no atomics).
// ------------------------------------------------------------------
typedef short v8s __attribute__((ext_vector_type(8)));
typedef float v4f __attribute__((ext_vector_type(4)));

typedef const __attribute__((address_space(1))) unsigned int* as1_cu32p;
typedef __attribute__((address_space(3))) unsigned int* as3_u32p;

__device__ __forceinline__ void gload_lds16(const unsigned short* g, unsigned short* l) {
  __builtin_amdgcn_global_load_lds((as1_cu32p)(uintptr_t)g,
                                   (as3_u32p)(uintptr_t)l, 16, 0, 0);
}

__global__ __launch_bounds__(256)
void gemm_mfma_bt(const unsigned short* __restrict__ A,
                  const unsigned short* __restrict__ B,
                  float* C, int NN, int K, int lda, int ldb, int ldc,
                  int KS, int Klen, long sliceStride) {
  __shared__ unsigned short As[128 * 32];
  __shared__ unsigned short Bs[128 * 32];

  int ks = blockIdx.z;
  int k0 = ks * Klen;
  int kend = min(K, k0 + Klen);
  float* Cs = C + (long)ks * sliceStride;

  int i0 = blockIdx.y * 128;
  int j0 = blockIdx.x * 128;

  int t = threadIdx.x;
  int wave = t >> 6, lane = t & 63;
  int wm = wave >> 1, wn = wave & 1;

  // staging: wave handles 32 rows of As and 32 rows of Bs (2 issues each)
  int srow = lane >> 2;     // 0..15
  int scol = lane & 3;      // k-chunk (8 bf16 = 16B)
  const unsigned short* gA0 = A + (long)(i0 + wave * 32 + srow) * lda + scol * 8;
  const unsigned short* gA1 = gA0 + (long)16 * lda;
  const unsigned short* gB0 = B + (long)(j0 + wave * 32 + srow) * ldb + scol * 8;
  const unsigned short* gB1 = gB0 + (long)16 * ldb;
  unsigned short* lA0 = As + (wave * 32) * 32;
  unsigned short* lA1 = As + (wave * 32 + 16) * 32;
  unsigned short* lB0 = Bs + (wave * 32) * 32;
  unsigned short* lB1 = Bs + (wave * 32 + 16) * 32;

  int fr = lane & 15;       // input-frag row index
  int kq = lane >> 4;       // k-quad (8 elements each)

  v4f acc[4][4] = {};

  for (int kt = k0; kt < kend; kt += 32) {
    gload_lds16(gA0 + kt, lA0);
    gload_lds16(gA1 + kt, lA1);
    gload_lds16(gB0 + kt, lB0);
    gload_lds16(gB1 + kt, lB1);
    __syncthreads();

    v8s af[4], bfr[4];
    #pragma unroll
    for (int mt = 0; mt < 4; mt++)
      af[mt] = *(const v8s*)&As[(wm * 64 + mt * 16 + fr) * 32 + kq * 8];
    #pragma unroll
    for (int nt = 0; nt < 4; nt++)
      bfr[nt] = *(const v8s*)&Bs[(wn * 64 + nt * 16 + fr) * 32 + kq * 8];

    #pragma unroll
    for (int mt = 0; mt < 4; mt++)
      #pragma unroll
      for (int nt = 0; nt < 4; nt++)
        acc[mt][nt] = __builtin_amdgcn_mfma_f32_16x16x32_bf16(
            af[mt], bfr[nt], acc[mt][nt], 0, 0, 0);
    __syncthreads();
  }

  // C/D layout: row=(lane>>4)*4+reg (A's m), col=lane&15 (B's n)
  int orow = (lane >> 4) * 4;
  int ocol = lane & 15;
  #pragma unroll
  for (int mt = 0; mt < 4; mt++) {
    #pragma unroll
    for (int nt = 0; nt < 4; nt++) {
      int gi = i0 + wm * 64 + mt * 16 + orow;
      int gj = j0 + wn * 64 + nt * 16 + ocol;
      if (gj >= NN) continue;
      #pragma unroll
      for (int r = 0; r < 4; r++) {
        long idx = (long)(gi + r) * ldc + gj;
        Cs[idx] = acc[mt][nt][r];
      }
    }
  }
}

// ------------------------------------------------------------------
// K6: depthwise causal conv (DCONV=4) + silu
// ------------------------------------------------------------------
__global__ void dwconv_silu(const float* __restrict__ xz,
                            const float4* __restrict__ cw,
                            const float* __restrict__ cb,
                            float* __restrict__ xc, int total) {
  int i = blockIdx.x * 256 + threadIdx.x;
  if (i >= total) return;
  int d  = i % DIc;
  int bl = i / DIc;
  int l  = bl % Lc;
  int b  = bl / Lc;
  float4 w = cw[d];
  float acc = cb[d];
  long rowbase = (long)(b * Lc) * E2c + d;
  int l0 = l - 3;
  if (l0     >= 0) acc += xz[rowbase + (long)l0       * E2c] * w.x;
  if (l0 + 1 >= 0) acc += xz[rowbase + (long)(l0 + 1) * E2c] * w.y;
  if (l0 + 2 >= 0) acc += xz[rowbase + (long)(l0 + 2) * E2c] * w.z;
  acc += xz[rowbase + (long)l * E2c] * w.w;
  xc[i] = acc / (1.f + expf(-acc));
}

// ------------------------------------------------------------------
// K9: selective scan. Reads dt-raw (f32), writes y (bf16) incl.
// *silu(z) and +u*D into yb (2048 x 4000 bf16).
// ------------------------------------------------------------------
__global__ void scan_kernel(const float* __restrict__ dtb,
                            const float* __restrict__ xdbl,
                            const float* __restrict__ xc,
                            const float* __restrict__ xz,
                            const float* __restrict__ A_log,
                            const float* __restrict__ D_p,
                            const float* __restrict__ b_dt,
                            unsigned short* __restrict__ yb) {
  int d = blockIdx.x * blockDim.x + threadIdx.x;
  int b = blockIdx.y;
  if (d >= DIc) return;
  float Av[Sc];
  #pragma unroll
  for (int s = 0; s < Sc; s++) Av[s] = -expf(A_log[d * Sc + s]);
  float Dp  = D_p[d];
  float bdt = b_dt[d];
  float h[Sc];
  #pragma unroll
  for (int s = 0; s < Sc; s++) h[s] = 0.f;

  for (int l = 0; l < Lc; l++) {
    long row = (long)(b * Lc + l);
    float dtr = dtb[row * DIc + d] + bdt;
    float dt  = fmaxf(dtr, 0.f) + log1pf(expf(-fabsf(dtr)));
    float u   = xc[row * DIc + d];
    float du  = dt * u;
    const float* xrow = xdbl + row * EXc;
    float y = 0.f;
    #pragma unroll
    for (int s = 0; s < Sc; s++) {
      float dA = expf(dt * Av[s]);
      h[s] = dA * h[s] + du * xrow[RKc + s];
      y += h[s] * xrow[RKc + Sc + s];
    }
    float zv = xz[row * E2c + DIc + d];
    float sz = zv / (1.f + expf(-zv));
    yb[row * DIc + d] = f2bf((y + u * Dp) * sz);
  }
}

// ------------------------------------------------------------------
// launch
// ------------------------------------------------------------------
extern "C" void kernel_launch(void* const* d_in, const int* in_sizes, int n_in,
                              void* d_out, int out_size, void* d_ws, size_t ws_size,
                              hipStream_t stream) {
  const float* x       = (const float*)d_in[0];
  const float* bn1_g   = (const float*)d_in[1];
  const float* bn1_b   = (const float*)d_in[2];
  const float* conv1_w = (const float*)d_in[3];
  const float* conv1_b = (const float*)d_in[4];
  const float* ln_w    = (const float*)d_in[5];
  const float* ln_b    = (const float*)d_in[6];
  const float* W_in    = (const float*)d_in[7];
  const float* convm_w = (const float*)d_in[8];
  const float* convm_b = (const float*)d_in[9];
  const float* W_x     = (const float*)d_in[10];
  const float* W_dt    = (const float*)d_in[11];
  const float* b_dt    = (const float*)d_in[12];
  const float* A_log   = (const float*)d_in[13];
  const float* D_p     = (const float*)d_in[14];
  const float* W_out   = (const float*)d_in[15];
  const float* bn3_g   = (const float*)d_in[16];
  const float* bn3_b   = (const float*)d_in[17];
  const float* conv3_w = (const float*)d_in[18];
  const float* conv3_b = (const float*)d_in[19];
  float* out = (float*)d_out;
  float* ws  = (float*)d_ws;

  const int TOT  = Bc * Cc * Nc;     // 4,096,000
  const int ROWS = Bc * Lc;          // 2048

  // ws layout (floats) — bf16 buffers live in dead regions:
  float* m1    = ws;                         // 2048
  float* v1    = ws + 2048;                  // 2048
  float* bnsc  = ws + 4096;                  // 128
  float* h     = ws + 8192;                  // 4,096,000 f32
  float* out1  = h    + (long)TOT;           // 4,096,000 f32
  float* outn  = out1 + (long)TOT;           // 4,096,000 f32 region
  float* xz    = outn + (long)TOT;           // 16,384,000 f32
  float* xc    = xz   + (long)ROWS * E2c;    // 8,192,000 f32
  float* xdbl  = xc   + (long)ROWS * DIc;    // 288,768 f32
  float* dtb   = xdbl + (long)ROWS * EXc;    // 8,192,000 f32

  // region reuse (lifetimes verified against stream order):
  unsigned short* An     = (unsigned short*)outn;  // 2048x2016 bf16; dead after W_in gemm
  unsigned short* Bwin   = (unsigned short*)dtb;   // 8064x2016 bf16; dead before dt-gemm writes dtb
  unsigned short* Bwout  = (unsigned short*)h;     // 2048x4000 bf16; h dead after conv1 gemm
  unsigned short* yb     = (unsigned short*)out;   // 2048x4000 bf16; d_out dead until conv3 gemm
  float* xdbl_sl = outn;                           // 8 slices x 288768 f32 (9.2MB<16.4MB); after W_in gemm
  float* wout_sl = xz;                             // 2 slices x 4,096,000 f32 (32.8MB<65.5MB); after scan

  dim3 b256(256);
  int gElem = (TOT + 255) / 256;

  // ---- block 1 ----
  inorm_stats<<<dim3(Bc * Cc), b256, 0, stream>>>(x, m1, v1);
  bn_scale<<<dim3(1), dim3(128), 0, stream>>>(v1, bnsc);
  compute_h<<<dim3(gElem), b256, 0, stream>>>(x, m1, v1, bnsc, bn1_g, bn1_b, h, TOT);
  { // out1[b][o][n] = sum_c w1[o][c]*h[b][c][n] + conv1_b[o]   (no split-K)
    dim3 g((Nc + GT - 1) / GT, 1, Bc);
    gemm_f32<false><<<g, b256, 0, stream>>>(conv1_w, h, out1, Cc, Nc, Cc,
                                            Cc, Nc, Nc,
                                            0L, (long)Cc * Nc, (long)Cc * Nc, 1, Cc,
                                            0L, conv1_b, nullptr);
  }

  // ---- layernorm -> bf16 An (K-padded) ----
  ln_rows<<<dim3(ROWS), b256, 0, stream>>>(out1, ln_w, ln_b, An);

  // ---- W_in -> bf16 padded (8064 x 2016), into dead dtb region ----
  {
    long tot = (long)NP1 * KP1;
    cvt_pad_bf16<<<dim3((unsigned)((tot + 255) / 256)), b256, 0, stream>>>(
        W_in, Bwin, NP1, KP1, E2c, Nc);
  }

  // ---- xz = outn @ W_in^T  (MFMA bf16, KS=1) ----
  {
    dim3 g(NP1 / 128, ROWS / 128, 1);
    gemm_mfma_bt<<<g, b256, 0, stream>>>(An, Bwin, xz, E2c, KP1, KP1, KP1, E2c,
                                         1, KP1, 0L);
  }

  // ---- depthwise conv + silu ----
  {
    int tot = ROWS * DIc;
    dwconv_silu<<<dim3((tot + 255) / 256), b256, 0, stream>>>(
        xz, (const float4*)convm_w, convm_b, xc, tot);
  }

  // ---- xdbl = xc @ W_x^T  (NN=141, split-K=8 plain slices + reduce) ----
  {
    dim3 g((EXc + GT - 1) / GT, (ROWS + GT - 1) / GT, 8);
    gemm_f32<true><<<g, b256, 0, stream>>>(xc, W_x, xdbl_sl, ROWS, EXc, DIc,
                                           DIc, DIc, EXc, 0L, 0L, 0L, 8, 500,
                                           (long)ROWS * EXc, nullptr, nullptr);
    int tot = ROWS * EXc;
    reduce_slices<<<dim3((tot + 255) / 256), b256, 0, stream>>>(
        xdbl_sl, xdbl, (long)ROWS * EXc, 8, tot, 0);
  }

  // ---- dt-raw = xdbl[:, :125] @ W_dt^T  (f32, KS=1) — overwrites Bwin ----
  {
    dim3 g((DIc + GT - 1) / GT, (ROWS + GT - 1) / GT, 1);
    gemm_f32<true><<<g, b256, 0, stream>>>(xdbl, W_dt, dtb, ROWS, DIc, RKc,
                                           EXc, RKc, DIc, 0L, 0L, 0L, 1, RKc,
                                           0L, nullptr, nullptr);
  }

  // ---- W_out -> bf16 padded (2048 x 4000), into dead h region ----
  {
    long tot = (long)2048 * DIc;
    cvt_pad_bf16<<<dim3((unsigned)((tot + 255) / 256)), b256, 0, stream>>>(
        W_out, Bwout, 2048, DIc, Nc, DIc);
  }

  // ---- selective scan -> yb bf16 (in d_out region) ----
  scan_kernel<<<dim3((DIc + 255) / 256, Bc), b256, 0, stream>>>(
      dtb, xdbl, xc, xz, A_log, D_p, b_dt, yb);

  // ---- y @ W_out^T  (MFMA bf16, KS=2 plain slices into dead xz region) ----
  {
    dim3 g(2048 / 128, ROWS / 128, 2);
    gemm_mfma_bt<<<g, b256, 0, stream>>>(yb, Bwout, wout_sl, Nc, DIc, DIc, DIc, Nc,
                                         2, 2048, (long)TOT);
    // out1 += slice0 + slice1  (residual)
    reduce_slices<<<dim3(gElem), b256, 0, stream>>>(
        wout_sl, out1, (long)TOT, 2, TOT, 1);
  }

  // ---- block 3 on out1 -> d_out = conv3(h3) + conv3_b + x ----
  inorm_stats<<<dim3(Bc * Cc), b256, 0, stream>>>(out1, m1, v1);
  bn_scale<<<dim3(1), dim3(128), 0, stream>>>(v1, bnsc);
  compute_h<<<dim3(gElem), b256, 0, stream>>>(out1, m1, v1, bnsc, bn3_g, bn3_b, h, TOT);
  {
    dim3 g((Nc + GT - 1) / GT, 1, Bc);
    gemm_f32<false><<<g, b256, 0, stream>>>(conv3_w, h, out, Cc, Nc, Cc,
                                            Cc, Nc, Nc,
                                            0L, (long)Cc * Nc, (long)Cc * Nc, 1, Cc,
                                            0L, conv3_b, x);
  }
}

// Round 5
// 903.799 us; speedup vs baseline: 3.6673x; 1.0548x over previous
//
#include <hip/hip_runtime.h>
#include <cmath>
#include <cstdint>

#define Bc   16
#define Cc   128
#define Nc   2000
#define Lc   128      // sequence length for mamba = C
#define DIc  4000
#define Sc   8
#define RKc  125      // DT_RANK
#define E2c  8000     // 2*DI
#define EXc  141      // DT_RANK + 2*S

// padded dims for MFMA gemm #1 (xz = outn @ W_in^T)
#define KP1  2016     // 2000 -> mult of 32
#define NP1  8064     // 8000 -> mult of 128

__device__ __forceinline__ unsigned short f2bf(float f) {
  union { float f; unsigned int u; } v; v.f = f;
  unsigned int r = v.u + 0x7FFFu + ((v.u >> 16) & 1u);
  return (unsigned short)(r >> 16);
}

// ------------------------------------------------------------------
// K1: per-(b,c) instance-norm stats over N (mean, biased var)
// ------------------------------------------------------------------
__global__ void inorm_stats(const float* __restrict__ in,
                            float* __restrict__ mout,
                            float* __restrict__ vout) {
  int bc = blockIdx.x;
  const float* p = in + (long)bc * Nc;
  float s = 0.f, sq = 0.f;
  for (int i = threadIdx.x; i < Nc; i += blockDim.x) {
    float x = p[i]; s += x; sq += x * x;
  }
  #pragma unroll
  for (int o = 32; o > 0; o >>= 1) {
    s  += __shfl_down(s, o, 64);
    sq += __shfl_down(sq, o, 64);
  }
  __shared__ float ss[4], sqq[4];
  int w = threadIdx.x >> 6, lane = threadIdx.x & 63;
  if (lane == 0) { ss[w] = s; sqq[w] = sq; }
  __syncthreads();
  if (threadIdx.x == 0) {
    s  = ss[0] + ss[1] + ss[2] + ss[3];
    sq = sqq[0] + sqq[1] + sqq[2] + sqq[3];
    float mean = s / Nc;
    float var  = sq / Nc - mean * mean;
    mout[bc] = mean; vout[bc] = var;
  }
}

// ------------------------------------------------------------------
// K2: bn scale; inorm output has zero mean per (b,c) so bn mean==0,
// bn var = avg_b[ v/(v+1e-3) ]
// ------------------------------------------------------------------
__global__ void bn_scale(const float* __restrict__ v, float* __restrict__ bnsc) {
  int c = threadIdx.x;
  if (c >= Cc) return;
  float s = 0.f;
  for (int b = 0; b < Bc; b++) {
    float vv = v[b * Cc + c];
    s += vv / (vv + 1e-3f);
  }
  bnsc[c] = rsqrtf(s / Bc + 1e-5f);
}

// ------------------------------------------------------------------
// K3: h = relu( inorm(x) * bnscale[c] * g[c] + b[c] )
// ------------------------------------------------------------------
__global__ void compute_h(const float* __restrict__ in,
                          const float* __restrict__ m,
                          const float* __restrict__ v,
                          const float* __restrict__ bnsc,
                          const float* __restrict__ g,
                          const float* __restrict__ bb,
                          float* __restrict__ h, int total) {
  int i = blockIdx.x * 256 + threadIdx.x;
  if (i >= total) return;
  int bc = i / Nc;
  int c  = bc % Cc;
  float xn  = (in[i] - m[bc]) * rsqrtf(v[bc] + 1e-3f);
  float val = xn * bnsc[c] * g[c] + bb[c];
  h[i] = fmaxf(val, 0.f);
}

// ------------------------------------------------------------------
// reduce ns slices (each `stride` apart) into dst; accum!=0 -> dst += sum
// ------------------------------------------------------------------
__global__ void reduce_slices(const float* __restrict__ sl, float* __restrict__ dst,
                              long stride, int ns, int total, int accum) {
  int i = blockIdx.x * 256 + threadIdx.x;
  if (i >= total) return;
  float s = accum ? dst[i] : 0.f;
  for (int k = 0; k < ns; k++) s += sl[(long)k * stride + i];
  dst[i] = s;
}

// ------------------------------------------------------------------
// reduce 4 xdbl slices (2048 x 256 each) -> xdbl f32 (2048 x 141)
// and xdbl_b bf16 (2048 x 128: cols 0..124 of xdbl, 125..127 zero)
// ------------------------------------------------------------------
__global__ void reduce_xdbl(const float* __restrict__ sl,
                            float* __restrict__ xd,
                            unsigned short* __restrict__ xdb) {
  int i = blockIdx.x * 256 + threadIdx.x;
  if (i >= 2048 * 144) return;
  int row = i / 144, c = i - row * 144;
  float s = 0.f;
  if (c < EXc) {
    #pragma unroll
    for (int k = 0; k < 4; k++) s += sl[(long)k * (2048 * 256) + (long)row * 256 + c];
    xd[(long)row * EXc + c] = s;
  }
  if (c < 128) xdb[(long)row * 128 + c] = f2bf(c < RKc ? s : 0.f);
}

// ------------------------------------------------------------------
// convert f32 (Rsrc x Csrc) to bf16 (R x Cdst) with zero padding
// ------------------------------------------------------------------
__global__ void cvt_pad_bf16(const float* __restrict__ src, unsigned short* __restrict__ dst,
                             int R, int Cdst, int Rsrc, int Csrc) {
  long i = (long)blockIdx.x * 256 + threadIdx.x;
  long total = (long)R * Cdst;
  if (i >= total) return;
  int r = (int)(i / Cdst), c = (int)(i - (long)r * Cdst);
  float v = (r < Rsrc && c < Csrc) ? src[(long)r * Csrc + c] : 0.f;
  dst[i] = f2bf(v);
}

// ------------------------------------------------------------------
// K4: LayerNorm rows -> writes bf16, K-padded to KP1 with zeros
// ------------------------------------------------------------------
__global__ void ln_rows(const float* __restrict__ in,
                        const float* __restrict__ lw,
                        const float* __restrict__ lb,
                        unsigned short* __restrict__ An) {
  int row = blockIdx.x;
  const float* p = in + (long)row * Nc;
  float s = 0.f, sq = 0.f;
  for (int i = threadIdx.x; i < Nc; i += blockDim.x) {
    float x = p[i]; s += x; sq += x * x;
  }
  #pragma unroll
  for (int o = 32; o > 0; o >>= 1) {
    s  += __shfl_down(s, o, 64);
    sq += __shfl_down(sq, o, 64);
  }
  __shared__ float ss[4], sqq[4];
  __shared__ float smean, srstd;
  int w = threadIdx.x >> 6, lane = threadIdx.x & 63;
  if (lane == 0) { ss[w] = s; sqq[w] = sq; }
  __syncthreads();
  if (threadIdx.x == 0) {
    s  = ss[0] + ss[1] + ss[2] + ss[3];
    sq = sqq[0] + sqq[1] + sqq[2] + sqq[3];
    float mean = s / Nc;
    float var  = sq / Nc - mean * mean;
    smean = mean; srstd = rsqrtf(var + 1e-5f);
  }
  __syncthreads();
  float mu = smean, rs = srstd;
  for (int i = threadIdx.x; i < KP1; i += blockDim.x) {
    float v = 0.f;
    if (i < Nc) v = (p[i] - mu) * rs * lw[i] + lb[i];
    An[(long)row * KP1 + i] = f2bf(v);
  }
}

// ------------------------------------------------------------------
// Generic f32 GEMM — plain stores only; epilogue folds bias + addp.
// ------------------------------------------------------------------
#define GT 128
#define GBK 16
template <bool BKMAJOR>
__global__ __launch_bounds__(256)
void gemm_f32(const float* __restrict__ Ag, const float* __restrict__ Bg,
              float* Cg, int M, int NN, int K, int lda, int ldb, int ldc,
              long sA, long sB, long sC, int KS, int Klen,
              long sliceStride, const float* __restrict__ bias,
              const float* __restrict__ addp) {
  int z = blockIdx.z;
  int batch = z / KS, ks = z - batch * KS;
  const float* A = Ag + (long)batch * sA;
  const float* B = Bg + (long)batch * sB;
  float* C = Cg + (long)batch * sC + (long)ks * sliceStride;
  const float* X = addp ? addp + (long)batch * sC : nullptr;
  int k0 = ks * Klen;
  int kend = min(K, k0 + Klen);

  int i0 = blockIdx.y * GT;
  int j0 = blockIdx.x * GT;

  __shared__ float As[GBK][GT + 4];
  __shared__ float Bs[GBK][GT + 4];

  int t = threadIdx.x;
  int jt = (t & 15) * 8;
  int it = (t >> 4) * 8;

  float acc[8][8] = {};

  for (int kt = k0; kt < kend; kt += GBK) {
    {
      int r  = t >> 1;
      int kb = (t & 1) * 8;
      int gi = i0 + r;
      #pragma unroll
      for (int u = 0; u < 8; u++) {
        int gk = kt + kb + u;
        float vv = 0.f;
        if (gi < M && gk < kend) vv = A[(long)gi * lda + gk];
        As[kb + u][r] = vv;
      }
    }
    if (BKMAJOR) {
      int r  = t >> 1;
      int kb = (t & 1) * 8;
      int gj = j0 + r;
      #pragma unroll
      for (int u = 0; u < 8; u++) {
        int gk = kt + kb + u;
        float vv = 0.f;
        if (gj < NN && gk < kend) vv = B[(long)gj * ldb + gk];
        Bs[kb + u][r] = vv;
      }
    } else {
      int kr = t >> 4;
      int jb = (t & 15) * 8;
      #pragma unroll
      for (int u = 0; u < 8; u++) {
        int gj = j0 + jb + u;
        float vv = 0.f;
        if (gj < NN && (kt + kr) < kend) vv = B[(long)(kt + kr) * ldb + gj];
        Bs[kr][jb + u] = vv;
      }
    }
    __syncthreads();
    #pragma unroll
    for (int kk = 0; kk < GBK; kk++) {
      float4 a0 = *(const float4*)&As[kk][it];
      float4 a1 = *(const float4*)&As[kk][it + 4];
      float4 b0 = *(const float4*)&Bs[kk][jt];
      float4 b1 = *(const float4*)&Bs[kk][jt + 4];
      float av[8] = {a0.x, a0.y, a0.z, a0.w, a1.x, a1.y, a1.z, a1.w};
      float bv[8] = {b0.x, b0.y, b0.z, b0.w, b1.x, b1.y, b1.z, b1.w};
      #pragma unroll
      for (int xi = 0; xi < 8; xi++)
        #pragma unroll
        for (int yi = 0; yi < 8; yi++)
          acc[xi][yi] += av[xi] * bv[yi];
    }
    __syncthreads();
  }

  #pragma unroll
  for (int xi = 0; xi < 8; xi++) {
    int gi = i0 + it + xi;
    if (gi >= M) continue;
    float bv = bias ? bias[gi] : 0.f;
    #pragma unroll
    for (int yi = 0; yi < 8; yi++) {
      int gj = j0 + jt + yi;
      if (gj >= NN) continue;
      long idx = (long)gi * ldc + gj;
      float v = acc[xi][yi] + bv;
      if (X) v += X[idx];
      C[idx] = v;
    }
  }
}

// ------------------------------------------------------------------
// bf16 MFMA GEMM, B^T layout: C[i][j] = sum_k A[i][k] * B[j][k]
// 128x128 tile, 4 waves (2x2), each wave 4x4 of mfma_f32_16x16x32_bf16.
// Split-K writes plain-store slices ks*sliceStride apart (no atomics).
// ------------------------------------------------------------------
typedef short v8s __attribute__((ext_vector_type(8)));
typedef float v4f __attribute__((ext_vector_type(4)));

typedef const __attribute__((address_space(1))) unsigned int* as1_cu32p;
typedef __attribute__((address_space(3))) unsigned int* as3_u32p;

__device__ __forceinline__ void gload_lds16(const unsigned short* g, unsigned short* l) {
  __builtin_amdgcn_global_load_lds((as1_cu32p)(uintptr_t)g,
                                   (as3_u32p)(uintptr_t)l, 16, 0, 0);
}

__global__ __launch_bounds__(256)
void gemm_mfma_bt(const unsigned short* __restrict__ A,
                  const unsigned short* __restrict__ B,
                  float* C, int NN, int K, int lda, int ldb, int ldc,
                  int KS, int Klen, long sliceStride) {
  __shared__ unsigned short As[128 * 32];
  __shared__ unsigned short Bs[128 * 32];

  int ks = blockIdx.z;
  int k0 = ks * Klen;
  int kend = min(K, k0 + Klen);
  float* Cs = C + (long)ks * sliceStride;

  int i0 = blockIdx.y * 128;
  int j0 = blockIdx.x * 128;

  int t = threadIdx.x;
  int wave = t >> 6, lane = t & 63;
  int wm = wave >> 1, wn = wave & 1;

  int srow = lane >> 2;     // 0..15
  int scol = lane & 3;      // k-chunk (8 bf16 = 16B)
  const unsigned short* gA0 = A + (long)(i0 + wave * 32 + srow) * lda + scol * 8;
  const unsigned short* gA1 = gA0 + (long)16 * lda;
  const unsigned short* gB0 = B + (long)(j0 + wave * 32 + srow) * ldb + scol * 8;
  const unsigned short* gB1 = gB0 + (long)16 * ldb;
  unsigned short* lA0 = As + (wave * 32) * 32;
  unsigned short* lA1 = As + (wave * 32 + 16) * 32;
  unsigned short* lB0 = Bs + (wave * 32) * 32;
  unsigned short* lB1 = Bs + (wave * 32 + 16) * 32;

  int fr = lane & 15;       // input-frag row index
  int kq = lane >> 4;       // k-quad (8 elements each)

  v4f acc[4][4] = {};

  for (int kt = k0; kt < kend; kt += 32) {
    gload_lds16(gA0 + kt, lA0);
    gload_lds16(gA1 + kt, lA1);
    gload_lds16(gB0 + kt, lB0);
    gload_lds16(gB1 + kt, lB1);
    __syncthreads();

    v8s af[4], bfr[4];
    #pragma unroll
    for (int mt = 0; mt < 4; mt++)
      af[mt] = *(const v8s*)&As[(wm * 64 + mt * 16 + fr) * 32 + kq * 8];
    #pragma unroll
    for (int nt = 0; nt < 4; nt++)
      bfr[nt] = *(const v8s*)&Bs[(wn * 64 + nt * 16 + fr) * 32 + kq * 8];

    #pragma unroll
    for (int mt = 0; mt < 4; mt++)
      #pragma unroll
      for (int nt = 0; nt < 4; nt++)
        acc[mt][nt] = __builtin_amdgcn_mfma_f32_16x16x32_bf16(
            af[mt], bfr[nt], acc[mt][nt], 0, 0, 0);
    __syncthreads();
  }

  // C/D layout: row=(lane>>4)*4+reg (A's m), col=lane&15 (B's n)
  int orow = (lane >> 4) * 4;
  int ocol = lane & 15;
  #pragma unroll
  for (int mt = 0; mt < 4; mt++) {
    #pragma unroll
    for (int nt = 0; nt < 4; nt++) {
      int gi = i0 + wm * 64 + mt * 16 + orow;
      int gj = j0 + wn * 64 + nt * 16 + ocol;
      if (gj >= NN) continue;
      #pragma unroll
      for (int r = 0; r < 4; r++) {
        long idx = (long)(gi + r) * ldc + gj;
        Cs[idx] = acc[mt][nt][r];
      }
    }
  }
}

// ------------------------------------------------------------------
// K6: depthwise causal conv (DCONV=4) + silu; writes f32 xc and bf16 xcb
// ------------------------------------------------------------------
__global__ void dwconv_silu(const float* __restrict__ xz,
                            const float4* __restrict__ cw,
                            const float* __restrict__ cb,
                            float* __restrict__ xc,
                            unsigned short* __restrict__ xcb, int total) {
  int i = blockIdx.x * 256 + threadIdx.x;
  if (i >= total) return;
  int d  = i % DIc;
  int bl = i / DIc;
  int l  = bl % Lc;
  int b  = bl / Lc;
  float4 w = cw[d];
  float acc = cb[d];
  long rowbase = (long)(b * Lc) * E2c + d;
  int l0 = l - 3;
  if (l0     >= 0) acc += xz[rowbase + (long)l0       * E2c] * w.x;
  if (l0 + 1 >= 0) acc += xz[rowbase + (long)(l0 + 1) * E2c] * w.y;
  if (l0 + 2 >= 0) acc += xz[rowbase + (long)(l0 + 2) * E2c] * w.z;
  acc += xz[rowbase + (long)l * E2c] * w.w;
  float sv = acc / (1.f + __expf(-acc));
  xc[i] = sv;
  xcb[i] = f2bf(sv);
}

// ------------------------------------------------------------------
// K9: selective scan, s-parallel. lane = (dl<<3)|s; each wave: 8 d x 8 s.
// block = 256 thr = 4 waves = 32 d. grid (125, 16) = 8000 waves.
// ------------------------------------------------------------------
__global__ __launch_bounds__(256)
void scan_kernel(const float* __restrict__ dtb,
                 const float* __restrict__ xdbl,
                 const float* __restrict__ xc,
                 const float* __restrict__ xz,
                 const float* __restrict__ A_log,
                 const float* __restrict__ D_p,
                 const float* __restrict__ b_dt,
                 unsigned short* __restrict__ yb) {
  int t = threadIdx.x;
  int wave = t >> 6, lane = t & 63;
  int dl = lane >> 3, s = lane & 7;
  int d = blockIdx.x * 32 + wave * 8 + dl;
  int b = blockIdx.y;

  float Av  = -__expf(A_log[d * Sc + s]);
  float bdt = b_dt[d];
  float Dp  = D_p[d];
  float h = 0.f;

  long rowd = (long)(b * Lc) * DIc + d;
  const float* xrow0 = xdbl + (long)(b * Lc) * EXc;

  for (int l = 0; l < Lc; l++) {
    float dtr = dtb[rowd] + bdt;
    float dtv = fmaxf(dtr, 0.f) + log1pf(__expf(-fabsf(dtr)));  // softplus
    float u   = xc[rowd];
    float Bv  = xrow0[(long)l * EXc + RKc + s];
    float Cv  = xrow0[(long)l * EXc + RKc + Sc + s];
    float dA  = __expf(dtv * Av);
    h = dA * h + (dtv * u) * Bv;
    float p = h * Cv;
    p += __shfl_xor(p, 1, 64);
    p += __shfl_xor(p, 2, 64);
    p += __shfl_xor(p, 4, 64);
    if (s == 0) {
      float zv = xz[(long)(b * Lc + l) * E2c + DIc + d];
      float sz = zv / (1.f + __expf(-zv));
      yb[rowd] = f2bf((p + u * Dp) * sz);
    }
    rowd += DIc;
  }
}

// ------------------------------------------------------------------
// launch
// ------------------------------------------------------------------
extern "C" void kernel_launch(void* const* d_in, const int* in_sizes, int n_in,
                              void* d_out, int out_size, void* d_ws, size_t ws_size,
                              hipStream_t stream) {
  const float* x       = (const float*)d_in[0];
  const float* bn1_g   = (const float*)d_in[1];
  const float* bn1_b   = (const float*)d_in[2];
  const float* conv1_w = (const float*)d_in[3];
  const float* conv1_b = (const float*)d_in[4];
  const float* ln_w    = (const float*)d_in[5];
  const float* ln_b    = (const float*)d_in[6];
  const float* W_in    = (const float*)d_in[7];
  const float* convm_w = (const float*)d_in[8];
  const float* convm_b = (const float*)d_in[9];
  const float* W_x     = (const float*)d_in[10];
  const float* W_dt    = (const float*)d_in[11];
  const float* b_dt    = (const float*)d_in[12];
  const float* A_log   = (const float*)d_in[13];
  const float* D_p     = (const float*)d_in[14];
  const float* W_out   = (const float*)d_in[15];
  const float* bn3_g   = (const float*)d_in[16];
  const float* bn3_b   = (const float*)d_in[17];
  const float* conv3_w = (const float*)d_in[18];
  const float* conv3_b = (const float*)d_in[19];
  float* out = (float*)d_out;
  float* ws  = (float*)d_ws;

  const int TOT  = Bc * Cc * Nc;     // 4,096,000
  const int ROWS = Bc * Lc;          // 2048

  // ws layout (floats):
  float* m1    = ws;                         // 2048
  float* v1    = ws + 2048;                  // 2048
  float* bnsc  = ws + 4096;                  // 128
  float* h     = ws + 8192;                  // 4,096,000 f32
  float* out1  = h    + (long)TOT;           // 4,096,000 f32
  float* outn  = out1 + (long)TOT;           // 4,096,000 f32 region
  float* xz    = outn + (long)TOT;           // 16,384,000 f32
  float* xc    = xz   + (long)ROWS * E2c;    // 8,192,000 f32
  float* xdbl  = xc   + (long)ROWS * DIc;    // 288,768 f32
  float* dtb   = xdbl + (long)ROWS * EXc;    // 8,192,000 f32

  // region reuse (stream-order lifetimes verified):
  unsigned short* An      = (unsigned short*)outn;        // live: ln_rows -> W_in gemm
  unsigned short* Bwin    = (unsigned short*)dtb;         // live: cvt -> W_in gemm (dt gemm later overwrites dtb)
  unsigned short* Bwx     = (unsigned short*)outn;                 // 256x4000 bf16 (after An dead)
  unsigned short* Bwdt    = (unsigned short*)(outn + 512000);      // 4096x128 bf16
  float*          xdbl_sl = outn + 800000;                         // 4 x 524288 f32
  unsigned short* xdbl_b  = (unsigned short*)(outn + 2900000);     // 2048x128 bf16
  unsigned short* xcb     = (unsigned short*)h;           // 2048x4000 bf16; live: dwconv -> xdbl gemm
  unsigned short* Bwout   = (unsigned short*)h;           // 2048x4000 bf16; live: cvt -> W_out gemm
  unsigned short* yb      = (unsigned short*)out;         // live: scan -> W_out gemm (conv3 overwrites out)
  float*          wout_sl = xz;                           // 2 x 4,096,000 f32; after scan reads xz

  dim3 b256(256);
  int gElem = (TOT + 255) / 256;

  // ---- block 1 ----
  inorm_stats<<<dim3(Bc * Cc), b256, 0, stream>>>(x, m1, v1);
  bn_scale<<<dim3(1), dim3(128), 0, stream>>>(v1, bnsc);
  compute_h<<<dim3(gElem), b256, 0, stream>>>(x, m1, v1, bnsc, bn1_g, bn1_b, h, TOT);
  { // out1 = conv1_w @ h + conv1_b
    dim3 g((Nc + GT - 1) / GT, 1, Bc);
    gemm_f32<false><<<g, b256, 0, stream>>>(conv1_w, h, out1, Cc, Nc, Cc,
                                            Cc, Nc, Nc,
                                            0L, (long)Cc * Nc, (long)Cc * Nc, 1, Cc,
                                            0L, conv1_b, nullptr);
  }

  // ---- layernorm -> bf16 An ----
  ln_rows<<<dim3(ROWS), b256, 0, stream>>>(out1, ln_w, ln_b, An);

  // ---- W_in -> bf16 padded (8064 x 2016) in dead dtb region ----
  {
    long tot = (long)NP1 * KP1;
    cvt_pad_bf16<<<dim3((unsigned)((tot + 255) / 256)), b256, 0, stream>>>(
        W_in, Bwin, NP1, KP1, E2c, Nc);
  }

  // ---- xz = outn @ W_in^T  (MFMA bf16) ----
  {
    dim3 g(NP1 / 128, ROWS / 128, 1);
    gemm_mfma_bt<<<g, b256, 0, stream>>>(An, Bwin, xz, E2c, KP1, KP1, KP1, E2c,
                                         1, KP1, 0L);
  }

  // ---- weight conversions for mamba-internal gemms (An now dead) ----
  cvt_pad_bf16<<<dim3((256 * 4000 + 255) / 256), b256, 0, stream>>>(
      W_x, Bwx, 256, 4000, EXc, DIc);
  cvt_pad_bf16<<<dim3((4096 * 128 + 255) / 256), b256, 0, stream>>>(
      W_dt, Bwdt, 4096, 128, DIc, RKc);

  // ---- depthwise conv + silu -> xc f32 + xcb bf16 ----
  {
    int tot = ROWS * DIc;
    dwconv_silu<<<dim3((tot + 255) / 256), b256, 0, stream>>>(
        xz, (const float4*)convm_w, convm_b, xc, xcb, tot);
  }

  // ---- xdbl = xc @ W_x^T  (MFMA bf16, KS=4 slices) ----
  {
    dim3 g(2, ROWS / 128, 4);
    gemm_mfma_bt<<<g, b256, 0, stream>>>(xcb, Bwx, xdbl_sl, 256, DIc,
                                         DIc, DIc, 256, 4, 1024, 2048L * 256);
    int tot = 2048 * 144;
    reduce_xdbl<<<dim3((tot + 255) / 256), b256, 0, stream>>>(xdbl_sl, xdbl, xdbl_b);
  }

  // ---- dt-raw = xdbl_b @ W_dt^T  (MFMA bf16, K=128) -> dtb f32 ----
  {
    dim3 g(4096 / 128, ROWS / 128, 1);
    gemm_mfma_bt<<<g, b256, 0, stream>>>(xdbl_b, Bwdt, dtb, DIc, 128,
                                         128, 128, DIc, 1, 128, 0L);
  }

  // ---- W_out -> bf16 (2048 x 4000) in h region (xcb dead) ----
  {
    long tot = (long)2048 * DIc;
    cvt_pad_bf16<<<dim3((unsigned)((tot + 255) / 256)), b256, 0, stream>>>(
        W_out, Bwout, 2048, DIc, Nc, DIc);
  }

  // ---- selective scan (s-parallel) -> yb bf16 ----
  scan_kernel<<<dim3(DIc / 32, Bc), b256, 0, stream>>>(
      dtb, xdbl, xc, xz, A_log, D_p, b_dt, yb);

  // ---- y @ W_out^T  (MFMA bf16, KS=2 slices in dead xz region) ----
  {
    dim3 g(2048 / 128, ROWS / 128, 2);
    gemm_mfma_bt<<<g, b256, 0, stream>>>(yb, Bwout, wout_sl, Nc, DIc, DIc, DIc, Nc,
                                         2, 2048, (long)TOT);
    reduce_slices<<<dim3(gElem), b256, 0, stream>>>(
        wout_sl, out1, (long)TOT, 2, TOT, 1);
  }

  // ---- block 3 on out1 -> d_out = conv3(h3) + conv3_b + x ----
  inorm_stats<<<dim3(Bc * Cc), b256, 0, stream>>>(out1, m1, v1);
  bn_scale<<<dim3(1), dim3(128), 0, stream>>>(v1, bnsc);
  compute_h<<<dim3(gElem), b256, 0, stream>>>(out1, m1, v1, bnsc, bn3_g, bn3_b, h, TOT);
  {
    dim3 g((Nc + GT - 1) / GT, 1, Bc);
    gemm_f32<false><<<g, b256, 0, stream>>>(conv3_w, h, out, Cc, Nc, Cc,
                                            Cc, Nc, Nc,
                                            0L, (long)Cc * Nc, (long)Cc * Nc, 1, Cc,
                                            0L, conv3_b, x);
  }
}

// Round 6
// 793.155 us; speedup vs baseline: 4.1788x; 1.1395x over previous
//
#include <hip/hip_runtime.h>
#include <cmath>
#include <cstdint>

#define Bc   16
#define Cc   128
#define Nc   2000
#define Lc   128      // sequence length for mamba = C
#define DIc  4000
#define Sc   8
#define RKc  125      // DT_RANK
#define E2c  8000     // 2*DI
#define EXc  141      // DT_RANK + 2*S

// padded dims for MFMA gemm #1 (xz = outn @ W_in^T)
#define KP1  2016     // 2000 -> mult of 32
#define NP1  8064     // 8000 -> mult of 128

__device__ __forceinline__ unsigned short f2bf(float f) {
  union { float f; unsigned int u; } v; v.f = f;
  unsigned int r = v.u + 0x7FFFu + ((v.u >> 16) & 1u);
  return (unsigned short)(r >> 16);
}

// ------------------------------------------------------------------
// K1: per-(b,c) instance-norm stats over N (mean, biased var)
// ------------------------------------------------------------------
__global__ void inorm_stats(const float* __restrict__ in,
                            float* __restrict__ mout,
                            float* __restrict__ vout) {
  int bc = blockIdx.x;
  const float* p = in + (long)bc * Nc;
  float s = 0.f, sq = 0.f;
  for (int i = threadIdx.x; i < Nc; i += blockDim.x) {
    float x = p[i]; s += x; sq += x * x;
  }
  #pragma unroll
  for (int o = 32; o > 0; o >>= 1) {
    s  += __shfl_down(s, o, 64);
    sq += __shfl_down(sq, o, 64);
  }
  __shared__ float ss[4], sqq[4];
  int w = threadIdx.x >> 6, lane = threadIdx.x & 63;
  if (lane == 0) { ss[w] = s; sqq[w] = sq; }
  __syncthreads();
  if (threadIdx.x == 0) {
    s  = ss[0] + ss[1] + ss[2] + ss[3];
    sq = sqq[0] + sqq[1] + sqq[2] + sqq[3];
    float mean = s / Nc;
    float var  = sq / Nc - mean * mean;
    mout[bc] = mean; vout[bc] = var;
  }
}

// ------------------------------------------------------------------
// K2: bn scale; inorm output has zero mean per (b,c) so bn mean==0,
// bn var = avg_b[ v/(v+1e-3) ]
// ------------------------------------------------------------------
__global__ void bn_scale(const float* __restrict__ v, float* __restrict__ bnsc) {
  int c = threadIdx.x;
  if (c >= Cc) return;
  float s = 0.f;
  for (int b = 0; b < Bc; b++) {
    float vv = v[b * Cc + c];
    s += vv / (vv + 1e-3f);
  }
  bnsc[c] = rsqrtf(s / Bc + 1e-5f);
}

// ------------------------------------------------------------------
// K3: h = relu( inorm(x) * bnscale[c] * g[c] + b[c] )
// ------------------------------------------------------------------
__global__ void compute_h(const float* __restrict__ in,
                          const float* __restrict__ m,
                          const float* __restrict__ v,
                          const float* __restrict__ bnsc,
                          const float* __restrict__ g,
                          const float* __restrict__ bb,
                          float* __restrict__ h, int total) {
  int i = blockIdx.x * 256 + threadIdx.x;
  if (i >= total) return;
  int bc = i / Nc;
  int c  = bc % Cc;
  float xn  = (in[i] - m[bc]) * rsqrtf(v[bc] + 1e-3f);
  float val = xn * bnsc[c] * g[c] + bb[c];
  h[i] = fmaxf(val, 0.f);
}

// ------------------------------------------------------------------
// reduce ns slices (each `stride` apart) into dst; accum!=0 -> dst += sum
// ------------------------------------------------------------------
__global__ void reduce_slices(const float* __restrict__ sl, float* __restrict__ dst,
                              long stride, int ns, int total, int accum) {
  int i = blockIdx.x * 256 + threadIdx.x;
  if (i >= total) return;
  float s = accum ? dst[i] : 0.f;
  for (int k = 0; k < ns; k++) s += sl[(long)k * stride + i];
  dst[i] = s;
}

// ------------------------------------------------------------------
// reduce 4 xdbl slices (2048 x 256 each) -> xdbl f32 (2048 x 141)
// and xdbl_b bf16 (2048 x 128: cols 0..124 of xdbl, 125..127 zero)
// ------------------------------------------------------------------
__global__ void reduce_xdbl(const float* __restrict__ sl,
                            float* __restrict__ xd,
                            unsigned short* __restrict__ xdb) {
  int i = blockIdx.x * 256 + threadIdx.x;
  if (i >= 2048 * 144) return;
  int row = i / 144, c = i - row * 144;
  float s = 0.f;
  if (c < EXc) {
    #pragma unroll
    for (int k = 0; k < 4; k++) s += sl[(long)k * (2048 * 256) + (long)row * 256 + c];
    xd[(long)row * EXc + c] = s;
  }
  if (c < 128) xdb[(long)row * 128 + c] = f2bf(c < RKc ? s : 0.f);
}

// ------------------------------------------------------------------
// convert f32 (Rsrc x Csrc) to bf16 (R x Cdst) with zero padding
// ------------------------------------------------------------------
__global__ void cvt_pad_bf16(const float* __restrict__ src, unsigned short* __restrict__ dst,
                             int R, int Cdst, int Rsrc, int Csrc) {
  long i = (long)blockIdx.x * 256 + threadIdx.x;
  long total = (long)R * Cdst;
  if (i >= total) return;
  int r = (int)(i / Cdst), c = (int)(i - (long)r * Cdst);
  float v = (r < Rsrc && c < Csrc) ? src[(long)r * Csrc + c] : 0.f;
  dst[i] = f2bf(v);
}

// ------------------------------------------------------------------
// K4: LayerNorm rows -> writes bf16, K-padded to KP1 with zeros
// ------------------------------------------------------------------
__global__ void ln_rows(const float* __restrict__ in,
                        const float* __restrict__ lw,
                        const float* __restrict__ lb,
                        unsigned short* __restrict__ An) {
  int row = blockIdx.x;
  const float* p = in + (long)row * Nc;
  float s = 0.f, sq = 0.f;
  for (int i = threadIdx.x; i < Nc; i += blockDim.x) {
    float x = p[i]; s += x; sq += x * x;
  }
  #pragma unroll
  for (int o = 32; o > 0; o >>= 1) {
    s  += __shfl_down(s, o, 64);
    sq += __shfl_down(sq, o, 64);
  }
  __shared__ float ss[4], sqq[4];
  __shared__ float smean, srstd;
  int w = threadIdx.x >> 6, lane = threadIdx.x & 63;
  if (lane == 0) { ss[w] = s; sqq[w] = sq; }
  __syncthreads();
  if (threadIdx.x == 0) {
    s  = ss[0] + ss[1] + ss[2] + ss[3];
    sq = sqq[0] + sqq[1] + sqq[2] + sqq[3];
    float mean = s / Nc;
    float var  = sq / Nc - mean * mean;
    smean = mean; srstd = rsqrtf(var + 1e-5f);
  }
  __syncthreads();
  float mu = smean, rs = srstd;
  for (int i = threadIdx.x; i < KP1; i += blockDim.x) {
    float v = 0.f;
    if (i < Nc) v = (p[i] - mu) * rs * lw[i] + lb[i];
    An[(long)row * KP1 + i] = f2bf(v);
  }
}

// ------------------------------------------------------------------
// Generic f32 GEMM — plain stores only; epilogue folds bias + addp.
// ------------------------------------------------------------------
#define GT 128
#define GBK 16
template <bool BKMAJOR>
__global__ __launch_bounds__(256)
void gemm_f32(const float* __restrict__ Ag, const float* __restrict__ Bg,
              float* Cg, int M, int NN, int K, int lda, int ldb, int ldc,
              long sA, long sB, long sC, int KS, int Klen,
              long sliceStride, const float* __restrict__ bias,
              const float* __restrict__ addp) {
  int z = blockIdx.z;
  int batch = z / KS, ks = z - batch * KS;
  const float* A = Ag + (long)batch * sA;
  const float* B = Bg + (long)batch * sB;
  float* C = Cg + (long)batch * sC + (long)ks * sliceStride;
  const float* X = addp ? addp + (long)batch * sC : nullptr;
  int k0 = ks * Klen;
  int kend = min(K, k0 + Klen);

  int i0 = blockIdx.y * GT;
  int j0 = blockIdx.x * GT;

  __shared__ float As[GBK][GT + 4];
  __shared__ float Bs[GBK][GT + 4];

  int t = threadIdx.x;
  int jt = (t & 15) * 8;
  int it = (t >> 4) * 8;

  float acc[8][8] = {};

  for (int kt = k0; kt < kend; kt += GBK) {
    {
      int r  = t >> 1;
      int kb = (t & 1) * 8;
      int gi = i0 + r;
      #pragma unroll
      for (int u = 0; u < 8; u++) {
        int gk = kt + kb + u;
        float vv = 0.f;
        if (gi < M && gk < kend) vv = A[(long)gi * lda + gk];
        As[kb + u][r] = vv;
      }
    }
    if (BKMAJOR) {
      int r  = t >> 1;
      int kb = (t & 1) * 8;
      int gj = j0 + r;
      #pragma unroll
      for (int u = 0; u < 8; u++) {
        int gk = kt + kb + u;
        float vv = 0.f;
        if (gj < NN && gk < kend) vv = B[(long)gj * ldb + gk];
        Bs[kb + u][r] = vv;
      }
    } else {
      int kr = t >> 4;
      int jb = (t & 15) * 8;
      #pragma unroll
      for (int u = 0; u < 8; u++) {
        int gj = j0 + jb + u;
        float vv = 0.f;
        if (gj < NN && (kt + kr) < kend) vv = B[(long)(kt + kr) * ldb + gj];
        Bs[kr][jb + u] = vv;
      }
    }
    __syncthreads();
    #pragma unroll
    for (int kk = 0; kk < GBK; kk++) {
      float4 a0 = *(const float4*)&As[kk][it];
      float4 a1 = *(const float4*)&As[kk][it + 4];
      float4 b0 = *(const float4*)&Bs[kk][jt];
      float4 b1 = *(const float4*)&Bs[kk][jt + 4];
      float av[8] = {a0.x, a0.y, a0.z, a0.w, a1.x, a1.y, a1.z, a1.w};
      float bv[8] = {b0.x, b0.y, b0.z, b0.w, b1.x, b1.y, b1.z, b1.w};
      #pragma unroll
      for (int xi = 0; xi < 8; xi++)
        #pragma unroll
        for (int yi = 0; yi < 8; yi++)
          acc[xi][yi] += av[xi] * bv[yi];
    }
    __syncthreads();
  }

  #pragma unroll
  for (int xi = 0; xi < 8; xi++) {
    int gi = i0 + it + xi;
    if (gi >= M) continue;
    float bv = bias ? bias[gi] : 0.f;
    #pragma unroll
    for (int yi = 0; yi < 8; yi++) {
      int gj = j0 + jt + yi;
      if (gj >= NN) continue;
      long idx = (long)gi * ldc + gj;
      float v = acc[xi][yi] + bv;
      if (X) v += X[idx];
      C[idx] = v;
    }
  }
}

// ------------------------------------------------------------------
// bf16 MFMA GEMM, B^T layout: C[i][j] = sum_k A[i][k] * B[j][k]
// 128x128 tile, 4 waves (2x2), each wave 4x4 of mfma_f32_16x16x32_bf16.
// Split-K writes plain-store slices ks*sliceStride apart (no atomics).
// epi: 0=none, 1=softplus(v + ebias[j]) (dt path), 2=silu(v) for j>=DIc
// ------------------------------------------------------------------
typedef short v8s __attribute__((ext_vector_type(8)));
typedef float v4f __attribute__((ext_vector_type(4)));

typedef const __attribute__((address_space(1))) unsigned int* as1_cu32p;
typedef __attribute__((address_space(3))) unsigned int* as3_u32p;

__device__ __forceinline__ void gload_lds16(const unsigned short* g, unsigned short* l) {
  __builtin_amdgcn_global_load_lds((as1_cu32p)(uintptr_t)g,
                                   (as3_u32p)(uintptr_t)l, 16, 0, 0);
}

__global__ __launch_bounds__(256)
void gemm_mfma_bt(const unsigned short* __restrict__ A,
                  const unsigned short* __restrict__ B,
                  float* C, int NN, int K, int lda, int ldb, int ldc,
                  int KS, int Klen, long sliceStride,
                  int epi, const float* __restrict__ ebias) {
  __shared__ unsigned short As[128 * 32];
  __shared__ unsigned short Bs[128 * 32];

  int ks = blockIdx.z;
  int k0 = ks * Klen;
  int kend = min(K, k0 + Klen);
  float* Cs = C + (long)ks * sliceStride;

  int i0 = blockIdx.y * 128;
  int j0 = blockIdx.x * 128;

  int t = threadIdx.x;
  int wave = t >> 6, lane = t & 63;
  int wm = wave >> 1, wn = wave & 1;

  int srow = lane >> 2;     // 0..15
  int scol = lane & 3;      // k-chunk (8 bf16 = 16B)
  const unsigned short* gA0 = A + (long)(i0 + wave * 32 + srow) * lda + scol * 8;
  const unsigned short* gA1 = gA0 + (long)16 * lda;
  const unsigned short* gB0 = B + (long)(j0 + wave * 32 + srow) * ldb + scol * 8;
  const unsigned short* gB1 = gB0 + (long)16 * ldb;
  unsigned short* lA0 = As + (wave * 32) * 32;
  unsigned short* lA1 = As + (wave * 32 + 16) * 32;
  unsigned short* lB0 = Bs + (wave * 32) * 32;
  unsigned short* lB1 = Bs + (wave * 32 + 16) * 32;

  int fr = lane & 15;       // input-frag row index
  int kq = lane >> 4;       // k-quad (8 elements each)

  v4f acc[4][4] = {};

  for (int kt = k0; kt < kend; kt += 32) {
    gload_lds16(gA0 + kt, lA0);
    gload_lds16(gA1 + kt, lA1);
    gload_lds16(gB0 + kt, lB0);
    gload_lds16(gB1 + kt, lB1);
    __syncthreads();

    v8s af[4], bfr[4];
    #pragma unroll
    for (int mt = 0; mt < 4; mt++)
      af[mt] = *(const v8s*)&As[(wm * 64 + mt * 16 + fr) * 32 + kq * 8];
    #pragma unroll
    for (int nt = 0; nt < 4; nt++)
      bfr[nt] = *(const v8s*)&Bs[(wn * 64 + nt * 16 + fr) * 32 + kq * 8];

    #pragma unroll
    for (int mt = 0; mt < 4; mt++)
      #pragma unroll
      for (int nt = 0; nt < 4; nt++)
        acc[mt][nt] = __builtin_amdgcn_mfma_f32_16x16x32_bf16(
            af[mt], bfr[nt], acc[mt][nt], 0, 0, 0);
    __syncthreads();
  }

  // C/D layout: row=(lane>>4)*4+reg (A's m), col=lane&15 (B's n)
  int orow = (lane >> 4) * 4;
  int ocol = lane & 15;
  #pragma unroll
  for (int mt = 0; mt < 4; mt++) {
    #pragma unroll
    for (int nt = 0; nt < 4; nt++) {
      int gi = i0 + wm * 64 + mt * 16 + orow;
      int gj = j0 + wn * 64 + nt * 16 + ocol;
      if (gj >= NN) continue;
      #pragma unroll
      for (int r = 0; r < 4; r++) {
        long idx = (long)(gi + r) * ldc + gj;
        float v = acc[mt][nt][r];
        if (epi == 1) {
          float tr = v + ebias[gj];
          v = fmaxf(tr, 0.f) + log1pf(__expf(-fabsf(tr)));  // softplus
        } else if (epi == 2) {
          if (gj >= DIc) v = v / (1.f + __expf(-v));        // silu on z half
        }
        Cs[idx] = v;
      }
    }
  }
}

// ------------------------------------------------------------------
// K6: depthwise causal conv (DCONV=4) + silu; writes f32 xc and bf16 xcb
// ------------------------------------------------------------------
__global__ void dwconv_silu(const float* __restrict__ xz,
                            const float4* __restrict__ cw,
                            const float* __restrict__ cb,
                            float* __restrict__ xc,
                            unsigned short* __restrict__ xcb, int total) {
  int i = blockIdx.x * 256 + threadIdx.x;
  if (i >= total) return;
  int d  = i % DIc;
  int bl = i / DIc;
  int l  = bl % Lc;
  int b  = bl / Lc;
  float4 w = cw[d];
  float acc = cb[d];
  long rowbase = (long)(b * Lc) * E2c + d;
  int l0 = l - 3;
  if (l0     >= 0) acc += xz[rowbase + (long)l0       * E2c] * w.x;
  if (l0 + 1 >= 0) acc += xz[rowbase + (long)(l0 + 1) * E2c] * w.y;
  if (l0 + 2 >= 0) acc += xz[rowbase + (long)(l0 + 2) * E2c] * w.z;
  acc += xz[rowbase + (long)l * E2c] * w.w;
  float sv = acc / (1.f + __expf(-acc));
  xc[i] = sv;
  xcb[i] = f2bf(sv);
}

// ------------------------------------------------------------------
// K9: selective scan, 1 thread per (b,d), software-pipelined.
// dtv = softplus(dt_raw + b_dt) precomputed in dt-GEMM epilogue.
// gz  = silu(z) precomputed in W_in-GEMM epilogue (xz cols >= DIc).
// Double-buffered groups of 4 steps: loads for group g+1 issued
// before computing group g (hides first-touch HBM latency).
// ------------------------------------------------------------------
#define SCU 4
__global__ __launch_bounds__(256)
void scan_kernel(const float* __restrict__ dtv,
                 const float* __restrict__ xdbl,
                 const float* __restrict__ xc,
                 const float* __restrict__ xzf,
                 const float* __restrict__ A_log,
                 const float* __restrict__ D_p,
                 unsigned short* __restrict__ yb) {
  int d = blockIdx.x * 256 + threadIdx.x;
  int b = blockIdx.y;
  if (d >= DIc) return;
  float Av[Sc];
  #pragma unroll
  for (int s = 0; s < Sc; s++) Av[s] = -__expf(A_log[d * Sc + s]);
  float Dp = D_p[d];
  float h[Sc];
  #pragma unroll
  for (int s = 0; s < Sc; s++) h[s] = 0.f;

  long base  = (long)(b * Lc) * DIc + d;
  long zbase = (long)(b * Lc) * E2c + DIc + d;
  const float* xrow = xdbl + (long)(b * Lc) * EXc + RKc;

  float d0[SCU], u0[SCU], z0[SCU], B0[SCU][Sc], C0[SCU][Sc];
  float d1[SCU], u1[SCU], z1[SCU], B1[SCU][Sc], C1[SCU][Sc];

#define LOADG(g, dd, uu, zz, BB, CC)                                        \
  { int l0_ = (g) * SCU;                                                    \
    _Pragma("unroll")                                                       \
    for (int u = 0; u < SCU; u++) {                                         \
      long idx = base + (long)(l0_ + u) * DIc;                              \
      dd[u] = dtv[idx];                                                     \
      uu[u] = xc[idx];                                                      \
      zz[u] = xzf[zbase + (long)(l0_ + u) * E2c];                           \
      const float* xr = xrow + (long)(l0_ + u) * EXc;                       \
      _Pragma("unroll")                                                     \
      for (int s = 0; s < Sc; s++) { BB[u][s] = xr[s]; CC[u][s] = xr[Sc + s]; } \
    } }

#define COMPG(g, dd, uu, zz, BB, CC)                                        \
  { int l0_ = (g) * SCU;                                                    \
    _Pragma("unroll")                                                       \
    for (int u = 0; u < SCU; u++) {                                         \
      float dv = dd[u], uv = uu[u];                                         \
      float du = dv * uv;                                                   \
      float p = 0.f;                                                        \
      _Pragma("unroll")                                                     \
      for (int s = 0; s < Sc; s++) {                                        \
        float dA = __expf(dv * Av[s]);                                      \
        h[s] = dA * h[s] + du * BB[u][s];                                   \
        p += h[s] * CC[u][s];                                               \
      }                                                                     \
      yb[base + (long)(l0_ + u) * DIc] = f2bf((p + uv * Dp) * zz[u]);       \
    } }

  LOADG(0, d0, u0, z0, B0, C0);
  #pragma unroll 1
  for (int g = 0; g < Lc / SCU; g += 2) {
    LOADG(g + 1, d1, u1, z1, B1, C1);
    COMPG(g, d0, u0, z0, B0, C0);
    if (g + 2 < Lc / SCU) LOADG(g + 2, d0, u0, z0, B0, C0);
    COMPG(g + 1, d1, u1, z1, B1, C1);
  }
#undef LOADG
#undef COMPG
}

// ------------------------------------------------------------------
// launch
// ------------------------------------------------------------------
extern "C" void kernel_launch(void* const* d_in, const int* in_sizes, int n_in,
                              void* d_out, int out_size, void* d_ws, size_t ws_size,
                              hipStream_t stream) {
  const float* x       = (const float*)d_in[0];
  const float* bn1_g   = (const float*)d_in[1];
  const float* bn1_b   = (const float*)d_in[2];
  const float* conv1_w = (const float*)d_in[3];
  const float* conv1_b = (const float*)d_in[4];
  const float* ln_w    = (const float*)d_in[5];
  const float* ln_b    = (const float*)d_in[6];
  const float* W_in    = (const float*)d_in[7];
  const float* convm_w = (const float*)d_in[8];
  const float* convm_b = (const float*)d_in[9];
  const float* W_x     = (const float*)d_in[10];
  const float* W_dt    = (const float*)d_in[11];
  const float* b_dt    = (const float*)d_in[12];
  const float* A_log   = (const float*)d_in[13];
  const float* D_p     = (const float*)d_in[14];
  const float* W_out   = (const float*)d_in[15];
  const float* bn3_g   = (const float*)d_in[16];
  const float* bn3_b   = (const float*)d_in[17];
  const float* conv3_w = (const float*)d_in[18];
  const float* conv3_b = (const float*)d_in[19];
  float* out = (float*)d_out;
  float* ws  = (float*)d_ws;

  const int TOT  = Bc * Cc * Nc;     // 4,096,000
  const int ROWS = Bc * Lc;          // 2048

  // ws layout (floats):
  float* m1    = ws;                         // 2048
  float* v1    = ws + 2048;                  // 2048
  float* bnsc  = ws + 4096;                  // 128
  float* h     = ws + 8192;                  // 4,096,000 f32
  float* out1  = h    + (long)TOT;           // 4,096,000 f32
  float* outn  = out1 + (long)TOT;           // 4,096,000 f32 region
  float* xz    = outn + (long)TOT;           // 16,384,000 f32
  float* xc    = xz   + (long)ROWS * E2c;    // 8,192,000 f32
  float* xdbl  = xc   + (long)ROWS * DIc;    // 288,768 f32
  float* dtb   = xdbl + (long)ROWS * EXc;    // 8,192,000 f32 (holds dtv after dt gemm)

  // region reuse (stream-order lifetimes verified):
  unsigned short* An      = (unsigned short*)outn;        // live: ln_rows -> W_in gemm
  unsigned short* Bwin    = (unsigned short*)dtb;         // live: cvt -> W_in gemm (dt gemm later overwrites dtb)
  unsigned short* Bwx     = (unsigned short*)outn;                 // 256x4000 bf16 (after An dead)
  unsigned short* Bwdt    = (unsigned short*)(outn + 512000);      // 4096x128 bf16
  float*          xdbl_sl = outn + 800000;                         // 4 x 524288 f32
  unsigned short* xdbl_b  = (unsigned short*)(outn + 2900000);     // 2048x128 bf16
  unsigned short* xcb     = (unsigned short*)h;           // 2048x4000 bf16; live: dwconv -> xdbl gemm
  unsigned short* Bwout   = (unsigned short*)h;           // 2048x4000 bf16; live: cvt -> W_out gemm
  unsigned short* yb      = (unsigned short*)out;         // live: scan -> W_out gemm (conv3 overwrites out)
  float*          wout_sl = xz;                           // 2 x 4,096,000 f32; after scan reads xz

  dim3 b256(256);
  int gElem = (TOT + 255) / 256;

  // ---- block 1 ----
  inorm_stats<<<dim3(Bc * Cc), b256, 0, stream>>>(x, m1, v1);
  bn_scale<<<dim3(1), dim3(128), 0, stream>>>(v1, bnsc);
  compute_h<<<dim3(gElem), b256, 0, stream>>>(x, m1, v1, bnsc, bn1_g, bn1_b, h, TOT);
  { // out1 = conv1_w @ h + conv1_b
    dim3 g((Nc + GT - 1) / GT, 1, Bc);
    gemm_f32<false><<<g, b256, 0, stream>>>(conv1_w, h, out1, Cc, Nc, Cc,
                                            Cc, Nc, Nc,
                                            0L, (long)Cc * Nc, (long)Cc * Nc, 1, Cc,
                                            0L, conv1_b, nullptr);
  }

  // ---- layernorm -> bf16 An ----
  ln_rows<<<dim3(ROWS), b256, 0, stream>>>(out1, ln_w, ln_b, An);

  // ---- W_in -> bf16 padded (8064 x 2016) in dead dtb region ----
  {
    long tot = (long)NP1 * KP1;
    cvt_pad_bf16<<<dim3((unsigned)((tot + 255) / 256)), b256, 0, stream>>>(
        W_in, Bwin, NP1, KP1, E2c, Nc);
  }

  // ---- xz = outn @ W_in^T  (MFMA bf16, epi=2: silu on z half) ----
  {
    dim3 g(NP1 / 128, ROWS / 128, 1);
    gemm_mfma_bt<<<g, b256, 0, stream>>>(An, Bwin, xz, E2c, KP1, KP1, KP1, E2c,
                                         1, KP1, 0L, 2, nullptr);
  }

  // ---- weight conversions for mamba-internal gemms (An now dead) ----
  cvt_pad_bf16<<<dim3((256 * 4000 + 255) / 256), b256, 0, stream>>>(
      W_x, Bwx, 256, 4000, EXc, DIc);
  cvt_pad_bf16<<<dim3((4096 * 128 + 255) / 256), b256, 0, stream>>>(
      W_dt, Bwdt, 4096, 128, DIc, RKc);

  // ---- depthwise conv + silu -> xc f32 + xcb bf16 ----
  {
    int tot = ROWS * DIc;
    dwconv_silu<<<dim3((tot + 255) / 256), b256, 0, stream>>>(
        xz, (const float4*)convm_w, convm_b, xc, xcb, tot);
  }

  // ---- xdbl = xc @ W_x^T  (MFMA bf16, KS=4 slices) ----
  {
    dim3 g(2, ROWS / 128, 4);
    gemm_mfma_bt<<<g, b256, 0, stream>>>(xcb, Bwx, xdbl_sl, 256, DIc,
                                         DIc, DIc, 256, 4, 1024, 2048L * 256,
                                         0, nullptr);
    int tot = 2048 * 144;
    reduce_xdbl<<<dim3((tot + 255) / 256), b256, 0, stream>>>(xdbl_sl, xdbl, xdbl_b);
  }

  // ---- dtv = softplus(xdbl_b @ W_dt^T + b_dt)  (MFMA bf16, epi=1) ----
  {
    dim3 g(4096 / 128, ROWS / 128, 1);
    gemm_mfma_bt<<<g, b256, 0, stream>>>(xdbl_b, Bwdt, dtb, DIc, 128,
                                         128, 128, DIc, 1, 128, 0L, 1, b_dt);
  }

  // ---- W_out -> bf16 (2048 x 4000) in h region (xcb dead) ----
  {
    long tot = (long)2048 * DIc;
    cvt_pad_bf16<<<dim3((unsigned)((tot + 255) / 256)), b256, 0, stream>>>(
        W_out, Bwout, 2048, DIc, Nc, DIc);
  }

  // ---- selective scan (pipelined, 1 thread/(b,d)) -> yb bf16 ----
  scan_kernel<<<dim3((DIc + 255) / 256, Bc), b256, 0, stream>>>(
      dtb, xdbl, xc, xz, A_log, D_p, yb);

  // ---- y @ W_out^T  (MFMA bf16, KS=2 slices in dead xz region) ----
  {
    dim3 g(2048 / 128, ROWS / 128, 2);
    gemm_mfma_bt<<<g, b256, 0, stream>>>(yb, Bwout, wout_sl, Nc, DIc, DIc, DIc, Nc,
                                         2, 2048, (long)TOT, 0, nullptr);
    reduce_slices<<<dim3(gElem), b256, 0, stream>>>(
        wout_sl, out1, (long)TOT, 2, TOT, 1);
  }

  // ---- block 3 on out1 -> d_out = conv3(h3) + conv3_b + x ----
  inorm_stats<<<dim3(Bc * Cc), b256, 0, stream>>>(out1, m1, v1);
  bn_scale<<<dim3(1), dim3(128), 0, stream>>>(v1, bnsc);
  compute_h<<<dim3(gElem), b256, 0, stream>>>(out1, m1, v1, bnsc, bn3_g, bn3_b, h, TOT);
  {
    dim3 g((Nc + GT - 1) / GT, 1, Bc);
    gemm_f32<false><<<g, b256, 0, stream>>>(conv3_w, h, out, Cc, Nc, Cc,
                                            Cc, Nc, Nc,
                                            0L, (long)Cc * Nc, (long)Cc * Nc, 1, Cc,
                                            0L, conv3_b, x);
  }
}

// Round 7
// 666.716 us; speedup vs baseline: 4.9713x; 1.1896x over previous
//
#include <hip/hip_runtime.h>
#include <cmath>
#include <cstdint>

#define Bc   16
#define Cc   128
#define Nc   2000
#define Lc   128      // sequence length for mamba = C
#define DIc  4000
#define Sc   8
#define RKc  125      // DT_RANK
#define E2c  8000     // 2*DI
#define EXc  141      // DT_RANK + 2*S

// padded dims for MFMA gemm #1 (xz = outn @ W_in^T)
#define KP1  2016     // 2000 -> mult of 32
#define NP1  8064     // 8000 -> mult of 128

__device__ __forceinline__ unsigned short f2bf(float f) {
  union { float f; unsigned int u; } v; v.f = f;
  unsigned int r = v.u + 0x7FFFu + ((v.u >> 16) & 1u);
  return (unsigned short)(r >> 16);
}

// ------------------------------------------------------------------
// K1: per-(b,c) instance-norm stats over N (mean, biased var)
// ------------------------------------------------------------------
__global__ void inorm_stats(const float* __restrict__ in,
                            float* __restrict__ mout,
                            float* __restrict__ vout) {
  int bc = blockIdx.x;
  const float* p = in + (long)bc * Nc;
  float s = 0.f, sq = 0.f;
  for (int i = threadIdx.x; i < Nc; i += blockDim.x) {
    float x = p[i]; s += x; sq += x * x;
  }
  #pragma unroll
  for (int o = 32; o > 0; o >>= 1) {
    s  += __shfl_down(s, o, 64);
    sq += __shfl_down(sq, o, 64);
  }
  __shared__ float ss[4], sqq[4];
  int w = threadIdx.x >> 6, lane = threadIdx.x & 63;
  if (lane == 0) { ss[w] = s; sqq[w] = sq; }
  __syncthreads();
  if (threadIdx.x == 0) {
    s  = ss[0] + ss[1] + ss[2] + ss[3];
    sq = sqq[0] + sqq[1] + sqq[2] + sqq[3];
    float mean = s / Nc;
    float var  = sq / Nc - mean * mean;
    mout[bc] = mean; vout[bc] = var;
  }
}

// ------------------------------------------------------------------
// K2: bn scale; inorm output has zero mean per (b,c) so bn mean==0,
// bn var = avg_b[ v/(v+1e-3) ]
// ------------------------------------------------------------------
__global__ void bn_scale(const float* __restrict__ v, float* __restrict__ bnsc) {
  int c = threadIdx.x;
  if (c >= Cc) return;
  float s = 0.f;
  for (int b = 0; b < Bc; b++) {
    float vv = v[b * Cc + c];
    s += vv / (vv + 1e-3f);
  }
  bnsc[c] = rsqrtf(s / Bc + 1e-5f);
}

// ------------------------------------------------------------------
// K3: h^T = relu( inorm(x) * bnscale[c] * g[c] + b[c] ) transposed to
// (b, n, c) bf16 via LDS tile — the MFMA B^T operand layout.
// grid (ceil(Nc/64)=32, Bc), block 256.
// ------------------------------------------------------------------
__global__ void compute_h_t(const float* __restrict__ in,
                            const float* __restrict__ m,
                            const float* __restrict__ v,
                            const float* __restrict__ bnsc,
                            const float* __restrict__ g,
                            const float* __restrict__ bb,
                            unsigned short* __restrict__ hT) {
  int b  = blockIdx.y;
  int n0 = blockIdx.x * 64;
  __shared__ unsigned short tile[64][132];
  int t  = threadIdx.x;
  int nl = t & 63, cb = t >> 6;
  int n  = n0 + nl;
  #pragma unroll 4
  for (int p = 0; p < 32; p++) {
    int c = p * 4 + cb;
    float val = 0.f;
    if (n < Nc) {
      int bc = b * Cc + c;
      float xn = (in[(long)bc * Nc + n] - m[bc]) * rsqrtf(v[bc] + 1e-3f);
      val = fmaxf(xn * bnsc[c] * g[c] + bb[c], 0.f);
    }
    tile[nl][c] = f2bf(val);
  }
  __syncthreads();
  int r = t >> 2, c0 = (t & 3) * 32;
  int nr = n0 + r;
  if (nr < Nc) {
    unsigned int* dst = (unsigned int*)(hT + ((long)b * 2048 + nr) * 128 + c0);
    const unsigned short* src = &tile[r][c0];
    #pragma unroll
    for (int j = 0; j < 16; j++)
      dst[j] = *(const unsigned int*)(src + 2 * j);
  }
}

// ------------------------------------------------------------------
// reduce ns slices (each `stride` apart) into dst; accum!=0 -> dst += sum
// ------------------------------------------------------------------
__global__ void reduce_slices(const float* __restrict__ sl, float* __restrict__ dst,
                              long stride, int ns, int total, int accum) {
  int i = blockIdx.x * 256 + threadIdx.x;
  if (i >= total) return;
  float s = accum ? dst[i] : 0.f;
  for (int k = 0; k < ns; k++) s += sl[(long)k * stride + i];
  dst[i] = s;
}

// ------------------------------------------------------------------
// reduce 4 xdbl slices (2048 x 256 each) -> xdbl f32 (2048 x 141)
// and xdbl_b bf16 (2048 x 128: cols 0..124, 125..127 zero)
// ------------------------------------------------------------------
__global__ void reduce_xdbl(const float* __restrict__ sl,
                            float* __restrict__ xd,
                            unsigned short* __restrict__ xdb) {
  int i = blockIdx.x * 256 + threadIdx.x;
  if (i >= 2048 * 144) return;
  int row = i / 144, c = i - row * 144;
  float s = 0.f;
  if (c < EXc) {
    #pragma unroll
    for (int k = 0; k < 4; k++) s += sl[(long)k * (2048 * 256) + (long)row * 256 + c];
    xd[(long)row * EXc + c] = s;
  }
  if (c < 128) xdb[(long)row * 128 + c] = f2bf(c < RKc ? s : 0.f);
}

// ------------------------------------------------------------------
// convert f32 (Rsrc x Csrc) to bf16 (R x Cdst) with zero padding
// ------------------------------------------------------------------
__global__ void cvt_pad_bf16(const float* __restrict__ src, unsigned short* __restrict__ dst,
                             int R, int Cdst, int Rsrc, int Csrc) {
  long i = (long)blockIdx.x * 256 + threadIdx.x;
  long total = (long)R * Cdst;
  if (i >= total) return;
  int r = (int)(i / Cdst), c = (int)(i - (long)r * Cdst);
  float v = (r < Rsrc && c < Csrc) ? src[(long)r * Csrc + c] : 0.f;
  dst[i] = f2bf(v);
}

// ------------------------------------------------------------------
// K4: LayerNorm rows -> writes bf16, K-padded to KP1 with zeros
// ------------------------------------------------------------------
__global__ void ln_rows(const float* __restrict__ in,
                        const float* __restrict__ lw,
                        const float* __restrict__ lb,
                        unsigned short* __restrict__ An) {
  int row = blockIdx.x;
  const float* p = in + (long)row * Nc;
  float s = 0.f, sq = 0.f;
  for (int i = threadIdx.x; i < Nc; i += blockDim.x) {
    float x = p[i]; s += x; sq += x * x;
  }
  #pragma unroll
  for (int o = 32; o > 0; o >>= 1) {
    s  += __shfl_down(s, o, 64);
    sq += __shfl_down(sq, o, 64);
  }
  __shared__ float ss[4], sqq[4];
  __shared__ float smean, srstd;
  int w = threadIdx.x >> 6, lane = threadIdx.x & 63;
  if (lane == 0) { ss[w] = s; sqq[w] = sq; }
  __syncthreads();
  if (threadIdx.x == 0) {
    s  = ss[0] + ss[1] + ss[2] + ss[3];
    sq = sqq[0] + sqq[1] + sqq[2] + sqq[3];
    float mean = s / Nc;
    float var  = sq / Nc - mean * mean;
    smean = mean; srstd = rsqrtf(var + 1e-5f);
  }
  __syncthreads();
  float mu = smean, rs = srstd;
  for (int i = threadIdx.x; i < KP1; i += blockDim.x) {
    float v = 0.f;
    if (i < Nc) v = (p[i] - mu) * rs * lw[i] + lb[i];
    An[(long)row * KP1 + i] = f2bf(v);
  }
}

// ------------------------------------------------------------------
// bf16 MFMA GEMM, B^T layout: C[i][j] = sum_k A[i][k] * B[j][k]
// 128x128 tile, 4 waves (2x2), each wave 4x4 of mfma_f32_16x16x32_bf16.
// blockIdx.z = batch*KS + ks; split-K writes plain-store slices.
// epi: 0 none; 1 softplus(v + ebias[gj]); 2 silu(v) for j>=DIc;
//      3 v + ebias[gi] (+ addp[idx] if addp) — conv epilogue.
// __launch_bounds__(256,4): cap regs at 128/wave -> 4 blocks/CU resident.
// ------------------------------------------------------------------
typedef short v8s __attribute__((ext_vector_type(8)));
typedef float v4f __attribute__((ext_vector_type(4)));

typedef const __attribute__((address_space(1))) unsigned int* as1_cu32p;
typedef __attribute__((address_space(3))) unsigned int* as3_u32p;

__device__ __forceinline__ void gload_lds16(const unsigned short* g, unsigned short* l) {
  __builtin_amdgcn_global_load_lds((as1_cu32p)(uintptr_t)g,
                                   (as3_u32p)(uintptr_t)l, 16, 0, 0);
}

__global__ __launch_bounds__(256, 4)
void gemm_mfma_bt(const unsigned short* __restrict__ A,
                  const unsigned short* __restrict__ B,
                  float* C, int NN, int K, int lda, int ldb, int ldc,
                  long sA, long sB, long sC,
                  int KS, int Klen, long sliceStride,
                  int epi, const float* __restrict__ ebias,
                  const float* __restrict__ addp) {
  __shared__ unsigned short As[128 * 32];
  __shared__ unsigned short Bs[128 * 32];

  int z = blockIdx.z;
  int batch = z / KS, ks = z - batch * KS;
  const unsigned short* Ab = A + (long)batch * sA;
  const unsigned short* Bb = B + (long)batch * sB;
  float* Cs = C + (long)batch * sC + (long)ks * sliceStride;
  const float* X = addp ? addp + (long)batch * sC : nullptr;

  int k0 = ks * Klen;
  int kend = min(K, k0 + Klen);

  int i0 = blockIdx.y * 128;
  int j0 = blockIdx.x * 128;

  int t = threadIdx.x;
  int wave = t >> 6, lane = t & 63;
  int wm = wave >> 1, wn = wave & 1;

  int srow = lane >> 2;     // 0..15
  int scol = lane & 3;      // k-chunk (8 bf16 = 16B)
  const unsigned short* gA0 = Ab + (long)(i0 + wave * 32 + srow) * lda + scol * 8;
  const unsigned short* gA1 = gA0 + (long)16 * lda;
  const unsigned short* gB0 = Bb + (long)(j0 + wave * 32 + srow) * ldb + scol * 8;
  const unsigned short* gB1 = gB0 + (long)16 * ldb;
  unsigned short* lA0 = As + (wave * 32) * 32;
  unsigned short* lA1 = As + (wave * 32 + 16) * 32;
  unsigned short* lB0 = Bs + (wave * 32) * 32;
  unsigned short* lB1 = Bs + (wave * 32 + 16) * 32;

  int fr = lane & 15;       // input-frag row index
  int kq = lane >> 4;       // k-quad (8 elements each)

  v4f acc[4][4] = {};

  for (int kt = k0; kt < kend; kt += 32) {
    gload_lds16(gA0 + kt, lA0);
    gload_lds16(gA1 + kt, lA1);
    gload_lds16(gB0 + kt, lB0);
    gload_lds16(gB1 + kt, lB1);
    __syncthreads();

    v8s af[4], bfr[4];
    #pragma unroll
    for (int mt = 0; mt < 4; mt++)
      af[mt] = *(const v8s*)&As[(wm * 64 + mt * 16 + fr) * 32 + kq * 8];
    #pragma unroll
    for (int nt = 0; nt < 4; nt++)
      bfr[nt] = *(const v8s*)&Bs[(wn * 64 + nt * 16 + fr) * 32 + kq * 8];

    #pragma unroll
    for (int mt = 0; mt < 4; mt++)
      #pragma unroll
      for (int nt = 0; nt < 4; nt++)
        acc[mt][nt] = __builtin_amdgcn_mfma_f32_16x16x32_bf16(
            af[mt], bfr[nt], acc[mt][nt], 0, 0, 0);
    __syncthreads();
  }

  // C/D layout: row=(lane>>4)*4+reg (A's m), col=lane&15 (B's n)
  int orow = (lane >> 4) * 4;
  int ocol = lane & 15;
  #pragma unroll
  for (int mt = 0; mt < 4; mt++) {
    #pragma unroll
    for (int nt = 0; nt < 4; nt++) {
      int gi = i0 + wm * 64 + mt * 16 + orow;
      int gj = j0 + wn * 64 + nt * 16 + ocol;
      if (gj >= NN) continue;
      #pragma unroll
      for (int r = 0; r < 4; r++) {
        long idx = (long)(gi + r) * ldc + gj;
        float v = acc[mt][nt][r];
        if (epi == 1) {
          float tr = v + ebias[gj];
          v = fmaxf(tr, 0.f) + log1pf(__expf(-fabsf(tr)));  // softplus
        } else if (epi == 2) {
          if (gj >= DIc) v = v / (1.f + __expf(-v));        // silu on z half
        } else if (epi == 3) {
          v += ebias[gi + r];
          if (X) v += X[idx];
        }
        Cs[idx] = v;
      }
    }
  }
}

// ------------------------------------------------------------------
// K6: depthwise causal conv (DCONV=4) + silu; writes f32 xc and bf16 xcb
// ------------------------------------------------------------------
__global__ void dwconv_silu(const float* __restrict__ xz,
                            const float4* __restrict__ cw,
                            const float* __restrict__ cb,
                            float* __restrict__ xc,
                            unsigned short* __restrict__ xcb, int total) {
  int i = blockIdx.x * 256 + threadIdx.x;
  if (i >= total) return;
  int d  = i % DIc;
  int bl = i / DIc;
  int l  = bl % Lc;
  int b  = bl / Lc;
  float4 w = cw[d];
  float acc = cb[d];
  long rowbase = (long)(b * Lc) * E2c + d;
  int l0 = l - 3;
  if (l0     >= 0) acc += xz[rowbase + (long)l0       * E2c] * w.x;
  if (l0 + 1 >= 0) acc += xz[rowbase + (long)(l0 + 1) * E2c] * w.y;
  if (l0 + 2 >= 0) acc += xz[rowbase + (long)(l0 + 2) * E2c] * w.z;
  acc += xz[rowbase + (long)l * E2c] * w.w;
  float sv = acc / (1.f + __expf(-acc));
  xc[i] = sv;
  xcb[i] = f2bf(sv);
}

// ------------------------------------------------------------------
// K9: selective scan, 1 thread per (b,d), software-pipelined.
// dtv pre-softplus'd (dt-GEMM epilogue); z pre-silu'd (W_in epilogue).
// ------------------------------------------------------------------
#define SCU 4
__global__ __launch_bounds__(256)
void scan_kernel(const float* __restrict__ dtv,
                 const float* __restrict__ xdbl,
                 const float* __restrict__ xc,
                 const float* __restrict__ xzf,
                 const float* __restrict__ A_log,
                 const float* __restrict__ D_p,
                 unsigned short* __restrict__ yb) {
  int d = blockIdx.x * 256 + threadIdx.x;
  int b = blockIdx.y;
  if (d >= DIc) return;
  float Av[Sc];
  #pragma unroll
  for (int s = 0; s < Sc; s++) Av[s] = -__expf(A_log[d * Sc + s]);
  float Dp = D_p[d];
  float h[Sc];
  #pragma unroll
  for (int s = 0; s < Sc; s++) h[s] = 0.f;

  long base  = (long)(b * Lc) * DIc + d;
  long zbase = (long)(b * Lc) * E2c + DIc + d;
  const float* xrow = xdbl + (long)(b * Lc) * EXc + RKc;

  float d0[SCU], u0[SCU], z0[SCU], B0[SCU][Sc], C0[SCU][Sc];
  float d1[SCU], u1[SCU], z1[SCU], B1[SCU][Sc], C1[SCU][Sc];

#define LOADG(g, dd, uu, zz, BB, CC)                                        \
  { int l0_ = (g) * SCU;                                                    \
    _Pragma("unroll")                                                       \
    for (int u = 0; u < SCU; u++) {                                         \
      long idx = base + (long)(l0_ + u) * DIc;                              \
      dd[u] = dtv[idx];                                                     \
      uu[u] = xc[idx];                                                      \
      zz[u] = xzf[zbase + (long)(l0_ + u) * E2c];                           \
      const float* xr = xrow + (long)(l0_ + u) * EXc;                       \
      _Pragma("unroll")                                                     \
      for (int s = 0; s < Sc; s++) { BB[u][s] = xr[s]; CC[u][s] = xr[Sc + s]; } \
    } }

#define COMPG(g, dd, uu, zz, BB, CC)                                        \
  { int l0_ = (g) * SCU;                                                    \
    _Pragma("unroll")                                                       \
    for (int u = 0; u < SCU; u++) {                                         \
      float dv = dd[u], uv = uu[u];                                         \
      float du = dv * uv;                                                   \
      float p = 0.f;                                                        \
      _Pragma("unroll")                                                     \
      for (int s = 0; s < Sc; s++) {                                        \
        float dA = __expf(dv * Av[s]);                                      \
        h[s] = dA * h[s] + du * BB[u][s];                                   \
        p += h[s] * CC[u][s];                                               \
      }                                                                     \
      yb[base + (long)(l0_ + u) * DIc] = f2bf((p + uv * Dp) * zz[u]);       \
    } }

  LOADG(0, d0, u0, z0, B0, C0);
  #pragma unroll 1
  for (int g = 0; g < Lc / SCU; g += 2) {
    LOADG(g + 1, d1, u1, z1, B1, C1);
    COMPG(g, d0, u0, z0, B0, C0);
    if (g + 2 < Lc / SCU) LOADG(g + 2, d0, u0, z0, B0, C0);
    COMPG(g + 1, d1, u1, z1, B1, C1);
  }
#undef LOADG
#undef COMPG
}

// ------------------------------------------------------------------
// launch
// ------------------------------------------------------------------
extern "C" void kernel_launch(void* const* d_in, const int* in_sizes, int n_in,
                              void* d_out, int out_size, void* d_ws, size_t ws_size,
                              hipStream_t stream) {
  const float* x       = (const float*)d_in[0];
  const float* bn1_g   = (const float*)d_in[1];
  const float* bn1_b   = (const float*)d_in[2];
  const float* conv1_w = (const float*)d_in[3];
  const float* conv1_b = (const float*)d_in[4];
  const float* ln_w    = (const float*)d_in[5];
  const float* ln_b    = (const float*)d_in[6];
  const float* W_in    = (const float*)d_in[7];
  const float* convm_w = (const float*)d_in[8];
  const float* convm_b = (const float*)d_in[9];
  const float* W_x     = (const float*)d_in[10];
  const float* W_dt    = (const float*)d_in[11];
  const float* b_dt    = (const float*)d_in[12];
  const float* A_log   = (const float*)d_in[13];
  const float* D_p     = (const float*)d_in[14];
  const float* W_out   = (const float*)d_in[15];
  const float* bn3_g   = (const float*)d_in[16];
  const float* bn3_b   = (const float*)d_in[17];
  const float* conv3_w = (const float*)d_in[18];
  const float* conv3_b = (const float*)d_in[19];
  float* out = (float*)d_out;
  float* ws  = (float*)d_ws;

  const int TOT  = Bc * Cc * Nc;     // 4,096,000
  const int ROWS = Bc * Lc;          // 2048

  // ws layout (floats):
  float* m1    = ws;                         // 2048
  float* v1    = ws + 2048;                  // 2048
  float* bnsc  = ws + 4096;                  // 128
  float* h     = ws + 8192;                  // 4,096,000 f32 region
  float* out1  = h    + (long)TOT;           // 4,096,000 f32
  float* outn  = out1 + (long)TOT;           // 4,096,000 f32 region
  float* xz    = outn + (long)TOT;           // 16,384,000 f32
  float* xc    = xz   + (long)ROWS * E2c;    // 8,192,000 f32
  float* xdbl  = xc   + (long)ROWS * DIc;    // 288,768 f32
  float* dtb   = xdbl + (long)ROWS * EXc;    // 8,192,000 f32 (holds dtv after dt gemm)

  // region reuse (stream-order lifetimes verified):
  unsigned short* An      = (unsigned short*)outn;             // [0, 2.07M fl); live: ln_rows -> W_in gemm
  unsigned short* Bwin    = (unsigned short*)dtb;              // live: cvt -> W_in gemm
  unsigned short* Bwx     = (unsigned short*)outn;             // [0, 512K fl); after An dead
  unsigned short* Bwdt    = (unsigned short*)(outn + 512000);  // [512K, 774K fl)
  float*          xdbl_sl = outn + 800000;                     // [800K, 2.90M fl)
  unsigned short* xdbl_b  = (unsigned short*)(outn + 2900000); // [2.90M, 3.04M fl)
  unsigned short* W1b     = (unsigned short*)(outn + 3100000); // 128x128 bf16
  unsigned short* W3b     = (unsigned short*)(outn + 3200000); // 128x128 bf16 (live to end; no later writes >3.04M)
  unsigned short* hT      = (unsigned short*)h;                // (16,2048,128) bf16 = 4.2M fl-equiv
  unsigned short* xcb     = (unsigned short*)h;                // 2048x4000 bf16; live: dwconv -> xdbl gemm
  unsigned short* Bwout   = (unsigned short*)h;                // 2048x4000 bf16; live: cvt -> W_out gemm
  unsigned short* yb      = (unsigned short*)out;              // live: scan -> W_out gemm
  float*          wout_sl = xz;                                // 2 x 4,096,000 f32; after scan reads xz

  dim3 b256(256);
  int gElem = (TOT + 255) / 256;

  // ---- block 1: inorm+bn+relu fused with transpose -> hT bf16 ----
  inorm_stats<<<dim3(Bc * Cc), b256, 0, stream>>>(x, m1, v1);
  bn_scale<<<dim3(1), dim3(128), 0, stream>>>(v1, bnsc);
  compute_h_t<<<dim3(32, Bc), b256, 0, stream>>>(x, m1, v1, bnsc, bn1_g, bn1_b, hT);
  cvt_pad_bf16<<<dim3(64), b256, 0, stream>>>(conv1_w, W1b, 128, 128, Cc, Cc);
  { // out1[b][o][n] = sum_c W1[o][c] * hT[b][n][c] + conv1_b[o]
    dim3 g(16, 1, Bc);
    gemm_mfma_bt<<<g, b256, 0, stream>>>(W1b, hT, out1, Nc, 128, 128, 128, Nc,
                                         0L, 2048L * 128, (long)Cc * Nc,
                                         1, 128, 0L, 3, conv1_b, nullptr);
  }

  // ---- layernorm -> bf16 An ----
  ln_rows<<<dim3(ROWS), b256, 0, stream>>>(out1, ln_w, ln_b, An);

  // ---- W_in -> bf16 padded (8064 x 2016) in dead dtb region ----
  {
    long tot = (long)NP1 * KP1;
    cvt_pad_bf16<<<dim3((unsigned)((tot + 255) / 256)), b256, 0, stream>>>(
        W_in, Bwin, NP1, KP1, E2c, Nc);
  }

  // ---- xz = outn @ W_in^T  (MFMA bf16, epi=2: silu on z half) ----
  {
    dim3 g(NP1 / 128, ROWS / 128, 1);
    gemm_mfma_bt<<<g, b256, 0, stream>>>(An, Bwin, xz, E2c, KP1, KP1, KP1, E2c,
                                         0L, 0L, 0L, 1, KP1, 0L, 2, nullptr, nullptr);
  }

  // ---- weight conversions for mamba-internal gemms (An now dead) ----
  cvt_pad_bf16<<<dim3((256 * 4000 + 255) / 256), b256, 0, stream>>>(
      W_x, Bwx, 256, 4000, EXc, DIc);
  cvt_pad_bf16<<<dim3((4096 * 128 + 255) / 256), b256, 0, stream>>>(
      W_dt, Bwdt, 4096, 128, DIc, RKc);

  // ---- depthwise conv + silu -> xc f32 + xcb bf16 (hT dead) ----
  {
    int tot = ROWS * DIc;
    dwconv_silu<<<dim3((tot + 255) / 256), b256, 0, stream>>>(
        xz, (const float4*)convm_w, convm_b, xc, xcb, tot);
  }

  // ---- xdbl = xc @ W_x^T  (MFMA bf16, KS=4 slices) ----
  {
    dim3 g(2, ROWS / 128, 4);
    gemm_mfma_bt<<<g, b256, 0, stream>>>(xcb, Bwx, xdbl_sl, 256, DIc,
                                         DIc, DIc, 256, 0L, 0L, 0L,
                                         4, 1024, 2048L * 256, 0, nullptr, nullptr);
    int tot = 2048 * 144;
    reduce_xdbl<<<dim3((tot + 255) / 256), b256, 0, stream>>>(xdbl_sl, xdbl, xdbl_b);
  }

  // ---- dtv = softplus(xdbl_b @ W_dt^T + b_dt)  (MFMA bf16, epi=1) ----
  {
    dim3 g(4096 / 128, ROWS / 128, 1);
    gemm_mfma_bt<<<g, b256, 0, stream>>>(xdbl_b, Bwdt, dtb, DIc, 128,
                                         128, 128, DIc, 0L, 0L, 0L,
                                         1, 128, 0L, 1, b_dt, nullptr);
  }

  // ---- W_out -> bf16 (2048 x 4000) in h region (xcb dead) ----
  {
    long tot = (long)2048 * DIc;
    cvt_pad_bf16<<<dim3((unsigned)((tot + 255) / 256)), b256, 0, stream>>>(
        W_out, Bwout, 2048, DIc, Nc, DIc);
  }

  // ---- selective scan (pipelined, 1 thread/(b,d)) -> yb bf16 ----
  scan_kernel<<<dim3((DIc + 255) / 256, Bc), b256, 0, stream>>>(
      dtb, xdbl, xc, xz, A_log, D_p, yb);

  // ---- y @ W_out^T  (MFMA bf16, KS=2 slices in dead xz region) ----
  {
    dim3 g(2048 / 128, ROWS / 128, 2);
    gemm_mfma_bt<<<g, b256, 0, stream>>>(yb, Bwout, wout_sl, Nc, DIc, DIc, DIc, Nc,
                                         0L, 0L, 0L, 2, 2048, (long)TOT,
                                         0, nullptr, nullptr);
    reduce_slices<<<dim3(gElem), b256, 0, stream>>>(
        wout_sl, out1, (long)TOT, 2, TOT, 1);
  }

  // ---- block 3 on out1 -> d_out = conv3(h3) + conv3_b + x ----
  inorm_stats<<<dim3(Bc * Cc), b256, 0, stream>>>(out1, m1, v1);
  bn_scale<<<dim3(1), dim3(128), 0, stream>>>(v1, bnsc);
  compute_h_t<<<dim3(32, Bc), b256, 0, stream>>>(out1, m1, v1, bnsc, bn3_g, bn3_b, hT);
  cvt_pad_bf16<<<dim3(64), b256, 0, stream>>>(conv3_w, W3b, 128, 128, Cc, Cc);
  {
    dim3 g(16, 1, Bc);
    gemm_mfma_bt<<<g, b256, 0, stream>>>(W3b, hT, out, Nc, 128, 128, 128, Nc,
                                         0L, 2048L * 128, (long)Cc * Nc,
                                         1, 128, 0L, 3, conv3_b, x);
  }
}